// Round 6
// baseline (2004.274 us; speedup 1.0000x reference)
//
#include <hip/hip_runtime.h>
#include <cstddef>

#define GAT_EPS 1e-16f
#define SCAN_BS 256

__device__ __forceinline__ float dot4(float4 a, float4 b) {
    return a.x * b.x + a.y * b.y + a.z * b.z + a.w * b.w;
}

// ---- histogram (in-degree) + edge_weight sums for self-loop fill='mean' ----
__global__ void k_deg(const int* __restrict__ dst, const float* __restrict__ ew,
                      float* __restrict__ sums, int* __restrict__ cnt, int E) {
    int i = blockIdx.x * blockDim.x + threadIdx.x;
    if (i < E) {
        int d = dst[i];
        atomicAdd(&sums[d], ew[i]);
        atomicAdd(&cnt[d], 1);
    }
}

__global__ void k_loopfin(const float* __restrict__ sums, const int* __restrict__ cnt,
                          float* __restrict__ loopat, int N) {
    int i = blockIdx.x * blockDim.x + threadIdx.x;
    if (i < N) loopat[i] = sums[i] / fmaxf((float)cnt[i], 1.0f);
}

// ---- per-head edge-attr dot constants ----
__global__ void k_wedot(const float* __restrict__ we1, const float* __restrict__ ae1,
                        const float* __restrict__ we2, const float* __restrict__ ae2,
                        float* __restrict__ wd) {
    int t = threadIdx.x;  // 128
    float v1 = we1[t] * ae1[t];
    float v2 = we2[t] * ae2[t];
#pragma unroll
    for (int off = 16; off; off >>= 1) {
        v1 += __shfl_xor(v1, off);
        v2 += __shfl_xor(v2, off);
    }
    if ((t & 31) == 0) { wd[t >> 5] = v1; wd[4 + (t >> 5)] = v2; }
}

// ---- exclusive scan of (cnt[i]+1) -> rowptr ----
__global__ void k_scanA(const int* __restrict__ cnt, int* __restrict__ incl,
                        int* __restrict__ bsum, int N) {
    __shared__ int sh[SCAN_BS];
    int i = blockIdx.x * SCAN_BS + threadIdx.x;
    int v = (i < N) ? cnt[i] + 1 : 0;
    sh[threadIdx.x] = v;
    __syncthreads();
    for (int off = 1; off < SCAN_BS; off <<= 1) {
        int t = (threadIdx.x >= off) ? sh[threadIdx.x - off] : 0;
        __syncthreads();
        sh[threadIdx.x] += t;
        __syncthreads();
    }
    if (i < N) incl[i] = sh[threadIdx.x];
    if (threadIdx.x == SCAN_BS - 1) bsum[blockIdx.x] = sh[threadIdx.x];
}

__global__ void k_scanB(int* __restrict__ bsum, int nb) {
    __shared__ int sh[512];
    int t = threadIdx.x;
    int v = (t < nb) ? bsum[t] : 0;
    sh[t] = v;
    __syncthreads();
    for (int off = 1; off < 512; off <<= 1) {
        int u = (t >= off) ? sh[t - off] : 0;
        __syncthreads();
        sh[t] += u;
        __syncthreads();
    }
    if (t < nb) bsum[t] = sh[t] - v;
}

__global__ void k_scanC(const int* __restrict__ cnt, const int* __restrict__ incl,
                        const int* __restrict__ bsum, int* __restrict__ rowptr,
                        int N, int Etot) {
    int i = blockIdx.x * SCAN_BS + threadIdx.x;
    if (i < N) rowptr[i] = bsum[blockIdx.x] + incl[i] - (cnt[i] + 1);
    if (i == N - 1) rowptr[N] = Etot;
}

// ---- scatter edges into CSR segments ----
__global__ void k_scatter(const int* __restrict__ src, const int* __restrict__ dst,
                          const float* __restrict__ ew, const float* __restrict__ loopat,
                          const int* __restrict__ rowptr, int* __restrict__ fill,
                          int* __restrict__ esrc, float* __restrict__ eea,
                          int E, int Etot) {
    int e = blockIdx.x * blockDim.x + threadIdx.x;
    if (e >= Etot) return;
    int s, d; float ea;
    if (e < E) { s = src[e]; d = dst[e]; ea = ew[e]; }
    else       { s = e - E; d = s;       ea = loopat[s]; }
    int pos = rowptr[d] + atomicAdd(&fill[d], 1);
    esrc[pos] = s;
    eea[pos] = ea;
}

// ---- layer-1 GEMM: xs = x @ W1^T (K=64). 64 rows x 64 cols per block,
//      16x16 threads, 4x4 outputs/thread (acc fits 64-VGPR tier, no spill). ----
__global__ void k_gemm1(const float* __restrict__ x, const float* __restrict__ W,
                        float* __restrict__ xs, int N) {
    int rb = blockIdx.x >> 1;
    int c0 = (blockIdx.x & 1) * 64;
    int n0 = rb * 64;
    int t = threadIdx.x;           // 256
    int tx = t & 15;               // col lane
    int ty = t >> 4;               // row group 0..15
    __shared__ float4 xsh[64 * 17];    // [row][kv] stride 17
    __shared__ float4 wsh[64 * 17];    // [c-c0][kv] stride 17
    int nrows = min(64, N - n0);
    const float4* xg = reinterpret_cast<const float4*>(x + (size_t)n0 * 64);
    for (int j = t; j < nrows * 16; j += 256) xsh[(j >> 4) * 17 + (j & 15)] = xg[j];
    const float4* Wg = reinterpret_cast<const float4*>(W + (size_t)c0 * 64);
    for (int j = t; j < 1024; j += 256) wsh[(j >> 4) * 17 + (j & 15)] = Wg[j];
    __syncthreads();

    float acc[4][4] = {};
    int r0 = ty * 4;
#pragma unroll
    for (int kv = 0; kv < 16; kv++) {
        float4 wv0 = wsh[(tx     ) * 17 + kv];
        float4 wv1 = wsh[(tx + 16) * 17 + kv];
        float4 wv2 = wsh[(tx + 32) * 17 + kv];
        float4 wv3 = wsh[(tx + 48) * 17 + kv];
#pragma unroll
        for (int i = 0; i < 4; i++) {
            float4 xv = xsh[(r0 + i) * 17 + kv];
            acc[i][0] += dot4(xv, wv0);
            acc[i][1] += dot4(xv, wv1);
            acc[i][2] += dot4(xv, wv2);
            acc[i][3] += dot4(xv, wv3);
        }
    }
#pragma unroll
    for (int i = 0; i < 4; i++) {
        int row = r0 + i;
        if (row < nrows) {
            float* o = xs + (size_t)(n0 + row) * 128 + c0 + tx;
            o[0]  = acc[i][0];
            o[16] = acc[i][1];
            o[32] = acc[i][2];
            o[48] = acc[i][3];
        }
    }
}

// ---- layer-2 GEMM: xs = h1 @ W2^T (K=32). 32 rows x 128 cols per block. ----
__global__ void k_gemm2(const float* __restrict__ h1, const float* __restrict__ W2,
                        float* __restrict__ xs, int N) {
    int n0 = blockIdx.x * 32;
    int t = threadIdx.x;           // 256
    int tx = t & 31;               // col lane
    int ty = t >> 5;               // row group 0..7
    __shared__ float4 xsh[32 * 9];     // [row][kv] stride 9
    __shared__ float4 wsh[128 * 9];    // [c][kv] stride 9
    int nrows = min(32, N - n0);
    const float4* xg = reinterpret_cast<const float4*>(h1 + (size_t)n0 * 32);
    for (int j = t; j < nrows * 8; j += 256) xsh[(j >> 3) * 9 + (j & 7)] = xg[j];
    const float4* Wg = reinterpret_cast<const float4*>(W2);   // 128*8 float4
    for (int j = t; j < 1024; j += 256) wsh[(j >> 3) * 9 + (j & 7)] = Wg[j];
    __syncthreads();

    float acc[4][4] = {};
    int r0 = ty * 4;
#pragma unroll
    for (int kv = 0; kv < 8; kv++) {
        float4 wv0 = wsh[(tx      ) * 9 + kv];
        float4 wv1 = wsh[(tx + 32 ) * 9 + kv];
        float4 wv2 = wsh[(tx + 64 ) * 9 + kv];
        float4 wv3 = wsh[(tx + 96 ) * 9 + kv];
#pragma unroll
        for (int i = 0; i < 4; i++) {
            float4 xv = xsh[(r0 + i) * 9 + kv];
            acc[i][0] += dot4(xv, wv0);
            acc[i][1] += dot4(xv, wv1);
            acc[i][2] += dot4(xv, wv2);
            acc[i][3] += dot4(xv, wv3);
        }
    }
#pragma unroll
    for (int i = 0; i < 4; i++) {
        int row = r0 + i;
        if (row < nrows) {
            float* o = xs + (size_t)(n0 + row) * 128 + tx;
            o[0]  = acc[i][0];
            o[32] = acc[i][1];
            o[64] = acc[i][2];
            o[96] = acc[i][3];
        }
    }
}

// ---- per-node a_src/a_dst head reductions (2 nodes per 256-thread block) ----
__global__ void k_attn(const float* __restrict__ xs, const float* __restrict__ as_,
                       const float* __restrict__ ad_, float* __restrict__ asrc,
                       float* __restrict__ adst, int N) {
    int n = blockIdx.x * 2 + (threadIdx.x >> 7);
    if (n >= N) return;
    int c = threadIdx.x & 127;
    float v = xs[(size_t)n * 128 + c];
    float vs = v * as_[c], vd = v * ad_[c];
#pragma unroll
    for (int off = 16; off; off >>= 1) {
        vs += __shfl_xor(vs, off);
        vd += __shfl_xor(vd, off);
    }
    if ((c & 31) == 0) {
        asrc[(size_t)n * 4 + (c >> 5)] = vs;
        adst[(size_t)n * 4 + (c >> 5)] = vd;
    }
}

// ---- fused gather: softmax-weighted aggregation + head-mean + bias + relu ----
__global__ void k_gather(const int* __restrict__ esrc, const float* __restrict__ eea,
                         const int* __restrict__ rowptr, const float* __restrict__ xs,
                         const float* __restrict__ asrc, const float* __restrict__ adst,
                         const float* __restrict__ wedot, const float* __restrict__ bias,
                         float* __restrict__ out, int N) {
    int node = blockIdx.x * (blockDim.x >> 6) + (threadIdx.x >> 6);
    if (node >= N) return;
    int l = threadIdx.x & 63;
    int h = l >> 4;
    float wd = wedot[h];
    float ad = adst[(size_t)node * 4 + h];
    int beg = rowptr[node], end = rowptr[node + 1];
    const float2* xs2 = reinterpret_cast<const float2*>(xs);

    float a0 = 0.f, a1 = 0.f, ds = 0.f;
    int s = esrc[beg];
    float ea = eea[beg];
    float as = asrc[(size_t)s * 4 + h];
    float2 v = xs2[(size_t)s * 64 + l];
    for (int i = beg; i < end; ++i) {
        int s1 = 0; float ea1 = 0.f, as1 = 0.f; float2 v1 = make_float2(0.f, 0.f);
        if (i + 1 < end) {
            s1 = esrc[i + 1];
            ea1 = eea[i + 1];
            as1 = asrc[(size_t)s1 * 4 + h];
            v1 = xs2[(size_t)s1 * 64 + l];
        }
        float al = as + ad + ea * wd;
        al = al > 0.f ? al : 0.2f * al;
        float w = expf(al);
        a0 += w * v.x;
        a1 += w * v.y;
        ds += w;
        s = s1; ea = ea1; as = as1; v = v1;
    }
    float inv = 1.f / (ds + GAT_EPS);
    a0 *= inv; a1 *= inv;
    a0 += __shfl_xor(a0, 16);
    a1 += __shfl_xor(a1, 16);
    a0 += __shfl_xor(a0, 32);
    a1 += __shfl_xor(a1, 32);
    if (l < 16) {
        int c0 = 2 * l;
        float r0 = fmaxf(0.25f * a0 + bias[c0], 0.f);
        float r1 = fmaxf(0.25f * a1 + bias[c0 + 1], 0.f);
        reinterpret_cast<float2*>(out)[(size_t)node * 16 + l] = make_float2(r0, r1);
    }
}

extern "C" void kernel_launch(void* const* d_in, const int* in_sizes, int n_in,
                              void* d_out, int out_size, void* d_ws, size_t ws_size,
                              hipStream_t stream) {
    const float* x   = (const float*)d_in[0];
    const int*   ei  = (const int*)d_in[1];
    const float* ewt = (const float*)d_in[2];
    const float* w1  = (const float*)d_in[3];
    const float* we1 = (const float*)d_in[4];
    const float* as1 = (const float*)d_in[5];
    const float* ad1 = (const float*)d_in[6];
    const float* ae1 = (const float*)d_in[7];
    const float* b1  = (const float*)d_in[8];
    const float* w2  = (const float*)d_in[9];
    const float* we2 = (const float*)d_in[10];
    const float* as2 = (const float*)d_in[11];
    const float* ad2 = (const float*)d_in[12];
    const float* ae2 = (const float*)d_in[13];
    const float* b2  = (const float*)d_in[14];

    const int N = in_sizes[0] / 64;
    const int E = in_sizes[1] / 2;
    const int Etot = E + N;
    const int* srcI = ei;
    const int* dstI = ei + E;
    const int nb = (N + SCAN_BS - 1) / SCAN_BS;

    char* base = (char*)d_ws;
    size_t off = 0;
    auto alloc = [&](size_t bytes) { char* p = base + off; off += (bytes + 15) & ~(size_t)15; return p; };
    float* xs     = (float*)alloc((size_t)N * 128 * sizeof(float));
    float* h1     = (float*)alloc((size_t)N * 32 * sizeof(float));
    float* asrc   = (float*)alloc((size_t)N * 4 * sizeof(float));
    float* adst   = (float*)alloc((size_t)N * 4 * sizeof(float));
    float* loopat = (float*)alloc((size_t)N * sizeof(float));
    float* sums   = (float*)alloc((size_t)N * sizeof(float));
    int*   cnt    = (int*)alloc((size_t)N * sizeof(int));
    int*   incl   = (int*)alloc((size_t)N * sizeof(int));
    int*   bsum   = (int*)alloc(512 * sizeof(int));
    int*   rowptr = (int*)alloc((size_t)(N + 1) * sizeof(int));
    int*   fill   = (int*)alloc((size_t)N * sizeof(int));
    int*   esrc   = (int*)alloc((size_t)Etot * sizeof(int));
    float* eea    = (float*)alloc((size_t)Etot * sizeof(float));
    float* wedot  = (float*)alloc(8 * sizeof(float));

    float* outF = (float*)d_out;

    hipMemsetAsync(sums, 0, (size_t)N * sizeof(float), stream);
    hipMemsetAsync(cnt, 0, (size_t)N * sizeof(int), stream);
    hipMemsetAsync(fill, 0, (size_t)N * sizeof(int), stream);

    // CSR build + self-loop attrs
    k_deg<<<(E + 255) / 256, 256, 0, stream>>>(dstI, ewt, sums, cnt, E);
    k_loopfin<<<(N + 255) / 256, 256, 0, stream>>>(sums, cnt, loopat, N);
    k_wedot<<<1, 128, 0, stream>>>(we1, ae1, we2, ae2, wedot);
    k_scanA<<<nb, SCAN_BS, 0, stream>>>(cnt, incl, bsum, N);
    k_scanB<<<1, 512, 0, stream>>>(bsum, nb);
    k_scanC<<<nb, SCAN_BS, 0, stream>>>(cnt, incl, bsum, rowptr, N, Etot);
    k_scatter<<<(Etot + 255) / 256, 256, 0, stream>>>(srcI, dstI, ewt, loopat,
                                                      rowptr, fill, esrc, eea, E, Etot);

    const int g1b = ((N + 63) / 64) * 2;
    const int g2b = (N + 31) / 32;
    const int attnb = (N + 1) / 2;
    const int gb = (N + 3) / 4;

    // layer 1
    k_gemm1<<<g1b, 256, 0, stream>>>(x, w1, xs, N);
    k_attn<<<attnb, 256, 0, stream>>>(xs, as1, ad1, asrc, adst, N);
    k_gather<<<gb, 256, 0, stream>>>(esrc, eea, rowptr, xs, asrc, adst,
                                     wedot + 0, b1, h1, N);

    // layer 2
    k_gemm2<<<g2b, 256, 0, stream>>>(h1, w2, xs, N);
    k_attn<<<attnb, 256, 0, stream>>>(xs, as2, ad2, asrc, adst, N);
    k_gather<<<gb, 256, 0, stream>>>(esrc, eea, rowptr, xs, asrc, adst,
                                     wedot + 4, b2, outF, N);
}

// Round 7
// 923.058 us; speedup vs baseline: 2.1713x; 2.1713x over previous
//
#include <hip/hip_runtime.h>
#include <cstddef>

#define GAT_EPS 1e-16f
#define SCAN_BS 256

// ---- histogram (in-degree) + edge_weight sums for self-loop fill='mean' ----
__global__ void k_deg(const int* __restrict__ dst, const float* __restrict__ ew,
                      float* __restrict__ sums, int* __restrict__ cnt, int E) {
    int i = blockIdx.x * blockDim.x + threadIdx.x;
    if (i < E) {
        int d = dst[i];
        atomicAdd(&sums[d], ew[i]);
        atomicAdd(&cnt[d], 1);
    }
}

__global__ void k_loopfin(const float* __restrict__ sums, const int* __restrict__ cnt,
                          float* __restrict__ loopat, int N) {
    int i = blockIdx.x * blockDim.x + threadIdx.x;
    if (i < N) loopat[i] = sums[i] / fmaxf((float)cnt[i], 1.0f);
}

// ---- per-head edge-attr dot constants ----
__global__ void k_wedot(const float* __restrict__ we1, const float* __restrict__ ae1,
                        const float* __restrict__ we2, const float* __restrict__ ae2,
                        float* __restrict__ wd) {
    int t = threadIdx.x;  // 128
    float v1 = we1[t] * ae1[t];
    float v2 = we2[t] * ae2[t];
#pragma unroll
    for (int off = 16; off; off >>= 1) {
        v1 += __shfl_xor(v1, off);
        v2 += __shfl_xor(v2, off);
    }
    if ((t & 31) == 0) { wd[t >> 5] = v1; wd[4 + (t >> 5)] = v2; }
}

// ---- exclusive scan of (cnt[i]+1) -> rowptr ----
__global__ void k_scanA(const int* __restrict__ cnt, int* __restrict__ incl,
                        int* __restrict__ bsum, int N) {
    __shared__ int sh[SCAN_BS];
    int i = blockIdx.x * SCAN_BS + threadIdx.x;
    int v = (i < N) ? cnt[i] + 1 : 0;
    sh[threadIdx.x] = v;
    __syncthreads();
    for (int off = 1; off < SCAN_BS; off <<= 1) {
        int t = (threadIdx.x >= off) ? sh[threadIdx.x - off] : 0;
        __syncthreads();
        sh[threadIdx.x] += t;
        __syncthreads();
    }
    if (i < N) incl[i] = sh[threadIdx.x];
    if (threadIdx.x == SCAN_BS - 1) bsum[blockIdx.x] = sh[threadIdx.x];
}

__global__ void k_scanB(int* __restrict__ bsum, int nb) {
    __shared__ int sh[512];
    int t = threadIdx.x;
    int v = (t < nb) ? bsum[t] : 0;
    sh[t] = v;
    __syncthreads();
    for (int off = 1; off < 512; off <<= 1) {
        int u = (t >= off) ? sh[t - off] : 0;
        __syncthreads();
        sh[t] += u;
        __syncthreads();
    }
    if (t < nb) bsum[t] = sh[t] - v;
}

__global__ void k_scanC(const int* __restrict__ cnt, const int* __restrict__ incl,
                        const int* __restrict__ bsum, int* __restrict__ rowptr,
                        int N, int Etot) {
    int i = blockIdx.x * SCAN_BS + threadIdx.x;
    if (i < N) rowptr[i] = bsum[blockIdx.x] + incl[i] - (cnt[i] + 1);
    if (i == N - 1) rowptr[N] = Etot;
}

// ---- scatter edges into CSR segments ----
__global__ void k_scatter(const int* __restrict__ src, const int* __restrict__ dst,
                          const float* __restrict__ ew, const float* __restrict__ loopat,
                          const int* __restrict__ rowptr, int* __restrict__ fill,
                          int* __restrict__ esrc, float* __restrict__ eea,
                          int E, int Etot) {
    int e = blockIdx.x * blockDim.x + threadIdx.x;
    if (e >= Etot) return;
    int s, d; float ea;
    if (e < E) { s = src[e]; d = dst[e]; ea = ew[e]; }
    else       { s = e - E; d = s;       ea = loopat[s]; }
    int pos = rowptr[d] + atomicAdd(&fill[d], 1);
    esrc[pos] = s;
    eea[pos] = ea;
}

// ---- layer-1 GEMM + fused attn dots: xs = x @ W1^T (K=64).
//      64 nodes per 256-thread block, scalar LDS tiles, tiny register state. ----
__global__ void k_gemm1(const float* __restrict__ x, const float* __restrict__ W,
                        const float* __restrict__ as_, const float* __restrict__ ad_,
                        float* __restrict__ xs, float* __restrict__ asrc,
                        float* __restrict__ adst, int N) {
    int n0 = blockIdx.x * 64;
    int t = threadIdx.x;          // 256
    int c = t & 127;              // output column
    int sub = t >> 7;             // row-half 0/1
    __shared__ float Wsh[128 * 65];   // [c][k] stride 65 -> 2-way bank (free)
    __shared__ float xsh[64 * 65];    // [row][k] stride 65, broadcast reads
    int nrows = min(64, N - n0);
    for (int j = t; j < 8192; j += 256) Wsh[(j >> 6) * 65 + (j & 63)] = W[j];
    const float* xg = x + (size_t)n0 * 64;
    for (int j = t; j < nrows * 64; j += 256) xsh[(j >> 6) * 65 + (j & 63)] = xg[j];
    __syncthreads();

    float asc = as_[c], adc = ad_[c];
    const float* wr = &Wsh[c * 65];
    for (int rp = 0; rp < 32; rp++) {
        int row = rp * 2 + sub;
        if (row >= nrows) break;
        const float* xr = &xsh[row * 65];
        float acc = 0.f;
#pragma unroll 8
        for (int k = 0; k < 64; k++) acc += xr[k] * wr[k];
        xs[(size_t)(n0 + row) * 128 + c] = acc;
        float vs = acc * asc, vd = acc * adc;
#pragma unroll
        for (int off = 16; off; off >>= 1) {
            vs += __shfl_xor(vs, off);
            vd += __shfl_xor(vd, off);
        }
        if ((c & 31) == 0) {
            asrc[(size_t)(n0 + row) * 4 + (c >> 5)] = vs;
            adst[(size_t)(n0 + row) * 4 + (c >> 5)] = vd;
        }
    }
}

// ---- layer-2 GEMM + fused attn dots: xs = h1 @ W2^T (K=32). ----
__global__ void k_gemm2(const float* __restrict__ h1, const float* __restrict__ W2,
                        const float* __restrict__ as_, const float* __restrict__ ad_,
                        float* __restrict__ xs, float* __restrict__ asrc,
                        float* __restrict__ adst, int N) {
    int n0 = blockIdx.x * 64;
    int t = threadIdx.x;
    int c = t & 127;
    int sub = t >> 7;
    __shared__ float Wsh[128 * 33];   // [c][k] stride 33
    __shared__ float xsh[64 * 33];    // [row][k] stride 33
    int nrows = min(64, N - n0);
    for (int j = t; j < 4096; j += 256) Wsh[(j >> 5) * 33 + (j & 31)] = W2[j];
    const float* xg = h1 + (size_t)n0 * 32;
    for (int j = t; j < nrows * 32; j += 256) xsh[(j >> 5) * 33 + (j & 31)] = xg[j];
    __syncthreads();

    float asc = as_[c], adc = ad_[c];
    const float* wr = &Wsh[c * 33];
    for (int rp = 0; rp < 32; rp++) {
        int row = rp * 2 + sub;
        if (row >= nrows) break;
        const float* xr = &xsh[row * 33];
        float acc = 0.f;
#pragma unroll 8
        for (int k = 0; k < 32; k++) acc += xr[k] * wr[k];
        xs[(size_t)(n0 + row) * 128 + c] = acc;
        float vs = acc * asc, vd = acc * adc;
#pragma unroll
        for (int off = 16; off; off >>= 1) {
            vs += __shfl_xor(vs, off);
            vd += __shfl_xor(vd, off);
        }
        if ((c & 31) == 0) {
            asrc[(size_t)(n0 + row) * 4 + (c >> 5)] = vs;
            adst[(size_t)(n0 + row) * 4 + (c >> 5)] = vd;
        }
    }
}

// ---- fused gather: softmax-weighted aggregation + head-mean + bias + relu ----
__global__ void k_gather(const int* __restrict__ esrc, const float* __restrict__ eea,
                         const int* __restrict__ rowptr, const float* __restrict__ xs,
                         const float* __restrict__ asrc, const float* __restrict__ adst,
                         const float* __restrict__ wedot, const float* __restrict__ bias,
                         float* __restrict__ out, int N) {
    int node = blockIdx.x * (blockDim.x >> 6) + (threadIdx.x >> 6);
    if (node >= N) return;
    int l = threadIdx.x & 63;
    int h = l >> 4;
    float wd = wedot[h];
    float ad = adst[(size_t)node * 4 + h];
    int beg = rowptr[node], end = rowptr[node + 1];
    const float2* xs2 = reinterpret_cast<const float2*>(xs);

    float a0 = 0.f, a1 = 0.f, ds = 0.f;
    int s = esrc[beg];
    float ea = eea[beg];
    float as = asrc[(size_t)s * 4 + h];
    float2 v = xs2[(size_t)s * 64 + l];
    for (int i = beg; i < end; ++i) {
        int s1 = 0; float ea1 = 0.f, as1 = 0.f; float2 v1 = make_float2(0.f, 0.f);
        if (i + 1 < end) {
            s1 = esrc[i + 1];
            ea1 = eea[i + 1];
            as1 = asrc[(size_t)s1 * 4 + h];
            v1 = xs2[(size_t)s1 * 64 + l];
        }
        float al = as + ad + ea * wd;
        al = al > 0.f ? al : 0.2f * al;
        float w = expf(al);
        a0 += w * v.x;
        a1 += w * v.y;
        ds += w;
        s = s1; ea = ea1; as = as1; v = v1;
    }
    float inv = 1.f / (ds + GAT_EPS);
    a0 *= inv; a1 *= inv;
    a0 += __shfl_xor(a0, 16);
    a1 += __shfl_xor(a1, 16);
    a0 += __shfl_xor(a0, 32);
    a1 += __shfl_xor(a1, 32);
    if (l < 16) {
        int c0 = 2 * l;
        float r0 = fmaxf(0.25f * a0 + bias[c0], 0.f);
        float r1 = fmaxf(0.25f * a1 + bias[c0 + 1], 0.f);
        reinterpret_cast<float2*>(out)[(size_t)node * 16 + l] = make_float2(r0, r1);
    }
}

extern "C" void kernel_launch(void* const* d_in, const int* in_sizes, int n_in,
                              void* d_out, int out_size, void* d_ws, size_t ws_size,
                              hipStream_t stream) {
    const float* x   = (const float*)d_in[0];
    const int*   ei  = (const int*)d_in[1];
    const float* ewt = (const float*)d_in[2];
    const float* w1  = (const float*)d_in[3];
    const float* we1 = (const float*)d_in[4];
    const float* as1 = (const float*)d_in[5];
    const float* ad1 = (const float*)d_in[6];
    const float* ae1 = (const float*)d_in[7];
    const float* b1  = (const float*)d_in[8];
    const float* w2  = (const float*)d_in[9];
    const float* we2 = (const float*)d_in[10];
    const float* as2 = (const float*)d_in[11];
    const float* ad2 = (const float*)d_in[12];
    const float* ae2 = (const float*)d_in[13];
    const float* b2  = (const float*)d_in[14];

    const int N = in_sizes[0] / 64;
    const int E = in_sizes[1] / 2;
    const int Etot = E + N;
    const int* srcI = ei;
    const int* dstI = ei + E;
    const int nb = (N + SCAN_BS - 1) / SCAN_BS;

    char* base = (char*)d_ws;
    size_t off = 0;
    auto alloc = [&](size_t bytes) { char* p = base + off; off += (bytes + 15) & ~(size_t)15; return p; };
    float* xs     = (float*)alloc((size_t)N * 128 * sizeof(float));
    float* h1     = (float*)alloc((size_t)N * 32 * sizeof(float));
    float* asrc   = (float*)alloc((size_t)N * 4 * sizeof(float));
    float* adst   = (float*)alloc((size_t)N * 4 * sizeof(float));
    float* loopat = (float*)alloc((size_t)N * sizeof(float));
    float* sums   = (float*)alloc((size_t)N * sizeof(float));
    int*   cnt    = (int*)alloc((size_t)N * sizeof(int));
    int*   incl   = (int*)alloc((size_t)N * sizeof(int));
    int*   bsum   = (int*)alloc(512 * sizeof(int));
    int*   rowptr = (int*)alloc((size_t)(N + 1) * sizeof(int));
    int*   fill   = (int*)alloc((size_t)N * sizeof(int));
    int*   esrc   = (int*)alloc((size_t)Etot * sizeof(int));
    float* eea    = (float*)alloc((size_t)Etot * sizeof(float));
    float* wedot  = (float*)alloc(8 * sizeof(float));

    float* outF = (float*)d_out;

    hipMemsetAsync(sums, 0, (size_t)N * sizeof(float), stream);
    hipMemsetAsync(cnt, 0, (size_t)N * sizeof(int), stream);
    hipMemsetAsync(fill, 0, (size_t)N * sizeof(int), stream);

    // CSR build + self-loop attrs
    k_deg<<<(E + 255) / 256, 256, 0, stream>>>(dstI, ewt, sums, cnt, E);
    k_loopfin<<<(N + 255) / 256, 256, 0, stream>>>(sums, cnt, loopat, N);
    k_wedot<<<1, 128, 0, stream>>>(we1, ae1, we2, ae2, wedot);
    k_scanA<<<nb, SCAN_BS, 0, stream>>>(cnt, incl, bsum, N);
    k_scanB<<<1, 512, 0, stream>>>(bsum, nb);
    k_scanC<<<nb, SCAN_BS, 0, stream>>>(cnt, incl, bsum, rowptr, N, Etot);
    k_scatter<<<(Etot + 255) / 256, 256, 0, stream>>>(srcI, dstI, ewt, loopat,
                                                      rowptr, fill, esrc, eea, E, Etot);

    const int gemmb = (N + 63) / 64;
    const int gb = (N + 3) / 4;

    // layer 1
    k_gemm1<<<gemmb, 256, 0, stream>>>(x, w1, as1, ad1, xs, asrc, adst, N);
    k_gather<<<gb, 256, 0, stream>>>(esrc, eea, rowptr, xs, asrc, adst,
                                     wedot + 0, b1, h1, N);

    // layer 2
    k_gemm2<<<gemmb, 256, 0, stream>>>(h1, w2, as2, ad2, xs, asrc, adst, N);
    k_gather<<<gb, 256, 0, stream>>>(esrc, eea, rowptr, xs, asrc, adst,
                                     wedot + 4, b2, outF, N);
}

// Round 8
// 711.823 us; speedup vs baseline: 2.8157x; 1.2968x over previous
//
#include <hip/hip_runtime.h>
#include <cstddef>

#define GAT_EPS 1e-16f
#define SCAN_BS 256

// ---- histogram (in-degree) + edge_weight sums for self-loop fill='mean' ----
__global__ void k_deg(const int* __restrict__ dst, const float* __restrict__ ew,
                      float* __restrict__ sums, int* __restrict__ cnt, int E) {
    int i = blockIdx.x * blockDim.x + threadIdx.x;
    if (i < E) {
        int d = dst[i];
        atomicAdd(&sums[d], ew[i]);
        atomicAdd(&cnt[d], 1);
    }
}

__global__ void k_loopfin(const float* __restrict__ sums, const int* __restrict__ cnt,
                          float* __restrict__ loopat, int N) {
    int i = blockIdx.x * blockDim.x + threadIdx.x;
    if (i < N) loopat[i] = sums[i] / fmaxf((float)cnt[i], 1.0f);
}

// ---- per-head edge-attr dot constants ----
__global__ void k_wedot(const float* __restrict__ we1, const float* __restrict__ ae1,
                        const float* __restrict__ we2, const float* __restrict__ ae2,
                        float* __restrict__ wd) {
    int t = threadIdx.x;  // 128
    float v1 = we1[t] * ae1[t];
    float v2 = we2[t] * ae2[t];
#pragma unroll
    for (int off = 16; off; off >>= 1) {
        v1 += __shfl_xor(v1, off);
        v2 += __shfl_xor(v2, off);
    }
    if ((t & 31) == 0) { wd[t >> 5] = v1; wd[4 + (t >> 5)] = v2; }
}

// ---- exclusive scan of (cnt[i]+1) -> rowptr ----
__global__ void k_scanA(const int* __restrict__ cnt, int* __restrict__ incl,
                        int* __restrict__ bsum, int N) {
    __shared__ int sh[SCAN_BS];
    int i = blockIdx.x * SCAN_BS + threadIdx.x;
    int v = (i < N) ? cnt[i] + 1 : 0;
    sh[threadIdx.x] = v;
    __syncthreads();
    for (int off = 1; off < SCAN_BS; off <<= 1) {
        int t = (threadIdx.x >= off) ? sh[threadIdx.x - off] : 0;
        __syncthreads();
        sh[threadIdx.x] += t;
        __syncthreads();
    }
    if (i < N) incl[i] = sh[threadIdx.x];
    if (threadIdx.x == SCAN_BS - 1) bsum[blockIdx.x] = sh[threadIdx.x];
}

__global__ void k_scanB(int* __restrict__ bsum, int nb) {
    __shared__ int sh[512];
    int t = threadIdx.x;
    int v = (t < nb) ? bsum[t] : 0;
    sh[t] = v;
    __syncthreads();
    for (int off = 1; off < 512; off <<= 1) {
        int u = (t >= off) ? sh[t - off] : 0;
        __syncthreads();
        sh[t] += u;
        __syncthreads();
    }
    if (t < nb) bsum[t] = sh[t] - v;
}

__global__ void k_scanC(const int* __restrict__ cnt, const int* __restrict__ incl,
                        const int* __restrict__ bsum, int* __restrict__ rowptr,
                        int N, int Etot) {
    int i = blockIdx.x * SCAN_BS + threadIdx.x;
    if (i < N) rowptr[i] = bsum[blockIdx.x] + incl[i] - (cnt[i] + 1);
    if (i == N - 1) rowptr[N] = Etot;
}

// ---- scatter edges into CSR segments ----
__global__ void k_scatter(const int* __restrict__ src, const int* __restrict__ dst,
                          const float* __restrict__ ew, const float* __restrict__ loopat,
                          const int* __restrict__ rowptr, int* __restrict__ fill,
                          int* __restrict__ esrc, float* __restrict__ eea,
                          int E, int Etot) {
    int e = blockIdx.x * blockDim.x + threadIdx.x;
    if (e >= Etot) return;
    int s, d; float ea;
    if (e < E) { s = src[e]; d = dst[e]; ea = ew[e]; }
    else       { s = e - E; d = s;       ea = loopat[s]; }
    int pos = rowptr[d] + atomicAdd(&fill[d], 1);
    esrc[pos] = s;
    eea[pos] = ea;
}

// ---- layer-1 GEMM + fused attn dots: xs = x @ W1^T (K=64).
//      64 rows x 128 cols per block; thread = 8 rows x 4 cols, scalar regs. ----
__global__ __launch_bounds__(256, 2)
void k_gemm1(const float* __restrict__ x, const float* __restrict__ W,
             const float* __restrict__ as_, const float* __restrict__ ad_,
             float* __restrict__ xs, float* __restrict__ asrc,
             float* __restrict__ adst, int N) {
    int n0 = blockIdx.x * 64;
    int t = threadIdx.x;          // 256
    int tx = t & 31;              // col lane
    int ty = t >> 5;              // row group 0..7
    __shared__ float Wsh[128 * 65];   // [c][k] stride 65 -> lanes hit distinct banks
    __shared__ float xsh[64 * 65];
    int nrows = min(64, N - n0);
    for (int j = t; j < 8192; j += 256) Wsh[(j >> 6) * 65 + (j & 63)] = W[j];
    const float* xg = x + (size_t)n0 * 64;
    for (int j = t; j < nrows * 64; j += 256) xsh[(j >> 6) * 65 + (j & 63)] = xg[j];
    __syncthreads();

    float acc[8][4];
#pragma unroll
    for (int i = 0; i < 8; i++)
#pragma unroll
        for (int j = 0; j < 4; j++) acc[i][j] = 0.f;

#pragma unroll 4
    for (int k = 0; k < 64; k++) {
        float w0 = Wsh[(tx     ) * 65 + k];
        float w1 = Wsh[(tx + 32) * 65 + k];
        float w2 = Wsh[(tx + 64) * 65 + k];
        float w3 = Wsh[(tx + 96) * 65 + k];
#pragma unroll
        for (int i = 0; i < 8; i++) {
            float xv = xsh[(ty * 8 + i) * 65 + k];
            acc[i][0] += xv * w0;
            acc[i][1] += xv * w1;
            acc[i][2] += xv * w2;
            acc[i][3] += xv * w3;
        }
    }

    float asv[4], adv[4];
#pragma unroll
    for (int j = 0; j < 4; j++) { asv[j] = as_[32 * j + tx]; adv[j] = ad_[32 * j + tx]; }

#pragma unroll
    for (int i = 0; i < 8; i++) {
        int row = ty * 8 + i;
        bool ok = row < nrows;
        float* orow = xs + (size_t)(n0 + row) * 128;
#pragma unroll
        for (int j = 0; j < 4; j++) {
            if (ok) orow[32 * j + tx] = acc[i][j];
            float vs = acc[i][j] * asv[j];
            float vd = acc[i][j] * adv[j];
#pragma unroll
            for (int off = 16; off; off >>= 1) {
                vs += __shfl_xor(vs, off);
                vd += __shfl_xor(vd, off);
            }
            if (ok && tx == 0) {
                asrc[(size_t)(n0 + row) * 4 + j] = vs;
                adst[(size_t)(n0 + row) * 4 + j] = vd;
            }
        }
    }
}

// ---- layer-2 GEMM + fused attn dots: xs = h1 @ W2^T (K=32). ----
__global__ __launch_bounds__(256, 2)
void k_gemm2(const float* __restrict__ h1, const float* __restrict__ W2,
             const float* __restrict__ as_, const float* __restrict__ ad_,
             float* __restrict__ xs, float* __restrict__ asrc,
             float* __restrict__ adst, int N) {
    int n0 = blockIdx.x * 64;
    int t = threadIdx.x;
    int tx = t & 31;
    int ty = t >> 5;
    __shared__ float Wsh[128 * 33];
    __shared__ float xsh[64 * 33];
    int nrows = min(64, N - n0);
    for (int j = t; j < 4096; j += 256) Wsh[(j >> 5) * 33 + (j & 31)] = W2[j];
    const float* xg = h1 + (size_t)n0 * 32;
    for (int j = t; j < nrows * 32; j += 256) xsh[(j >> 5) * 33 + (j & 31)] = xg[j];
    __syncthreads();

    float acc[8][4];
#pragma unroll
    for (int i = 0; i < 8; i++)
#pragma unroll
        for (int j = 0; j < 4; j++) acc[i][j] = 0.f;

#pragma unroll 4
    for (int k = 0; k < 32; k++) {
        float w0 = Wsh[(tx     ) * 33 + k];
        float w1 = Wsh[(tx + 32) * 33 + k];
        float w2 = Wsh[(tx + 64) * 33 + k];
        float w3 = Wsh[(tx + 96) * 33 + k];
#pragma unroll
        for (int i = 0; i < 8; i++) {
            float xv = xsh[(ty * 8 + i) * 33 + k];
            acc[i][0] += xv * w0;
            acc[i][1] += xv * w1;
            acc[i][2] += xv * w2;
            acc[i][3] += xv * w3;
        }
    }

    float asv[4], adv[4];
#pragma unroll
    for (int j = 0; j < 4; j++) { asv[j] = as_[32 * j + tx]; adv[j] = ad_[32 * j + tx]; }

#pragma unroll
    for (int i = 0; i < 8; i++) {
        int row = ty * 8 + i;
        bool ok = row < nrows;
        float* orow = xs + (size_t)(n0 + row) * 128;
#pragma unroll
        for (int j = 0; j < 4; j++) {
            if (ok) orow[32 * j + tx] = acc[i][j];
            float vs = acc[i][j] * asv[j];
            float vd = acc[i][j] * adv[j];
#pragma unroll
            for (int off = 16; off; off >>= 1) {
                vs += __shfl_xor(vs, off);
                vd += __shfl_xor(vd, off);
            }
            if (ok && tx == 0) {
                asrc[(size_t)(n0 + row) * 4 + j] = vs;
                adst[(size_t)(n0 + row) * 4 + j] = vd;
            }
        }
    }
}

// ---- fused gather: softmax-weighted aggregation + head-mean + bias + relu.
//      One 64-lane wave per node, 2 edges per loop iteration for MLP. ----
__global__ void k_gather(const int* __restrict__ esrc, const float* __restrict__ eea,
                         const int* __restrict__ rowptr, const float* __restrict__ xs,
                         const float* __restrict__ asrc, const float* __restrict__ adst,
                         const float* __restrict__ wedot, const float* __restrict__ bias,
                         float* __restrict__ out, int N) {
    int node = blockIdx.x * (blockDim.x >> 6) + (threadIdx.x >> 6);
    if (node >= N) return;
    int l = threadIdx.x & 63;
    int h = l >> 4;
    float wd = wedot[h];
    float ad = adst[(size_t)node * 4 + h];
    int beg = rowptr[node], end = rowptr[node + 1];
    const float2* xs2 = reinterpret_cast<const float2*>(xs);

    float a0 = 0.f, a1 = 0.f, ds = 0.f;
    int i = beg;
    for (; i + 1 < end; i += 2) {
        int sA = esrc[i], sB = esrc[i + 1];
        float eaA = eea[i], eaB = eea[i + 1];
        float asA = asrc[(size_t)sA * 4 + h];
        float asB = asrc[(size_t)sB * 4 + h];
        float2 vA = xs2[(size_t)sA * 64 + l];
        float2 vB = xs2[(size_t)sB * 64 + l];
        float alA = asA + ad + eaA * wd;
        alA = alA > 0.f ? alA : 0.2f * alA;
        float alB = asB + ad + eaB * wd;
        alB = alB > 0.f ? alB : 0.2f * alB;
        float wA = __expf(alA);
        float wB = __expf(alB);
        a0 += wA * vA.x + wB * vB.x;
        a1 += wA * vA.y + wB * vB.y;
        ds += wA + wB;
    }
    if (i < end) {
        int s = esrc[i];
        float ea = eea[i];
        float as = asrc[(size_t)s * 4 + h];
        float2 v = xs2[(size_t)s * 64 + l];
        float al = as + ad + ea * wd;
        al = al > 0.f ? al : 0.2f * al;
        float w = __expf(al);
        a0 += w * v.x;
        a1 += w * v.y;
        ds += w;
    }
    float inv = 1.f / (ds + GAT_EPS);
    a0 *= inv; a1 *= inv;
    a0 += __shfl_xor(a0, 16);
    a1 += __shfl_xor(a1, 16);
    a0 += __shfl_xor(a0, 32);
    a1 += __shfl_xor(a1, 32);
    if (l < 16) {
        int c0 = 2 * l;
        float r0 = fmaxf(0.25f * a0 + bias[c0], 0.f);
        float r1 = fmaxf(0.25f * a1 + bias[c0 + 1], 0.f);
        reinterpret_cast<float2*>(out)[(size_t)node * 16 + l] = make_float2(r0, r1);
    }
}

extern "C" void kernel_launch(void* const* d_in, const int* in_sizes, int n_in,
                              void* d_out, int out_size, void* d_ws, size_t ws_size,
                              hipStream_t stream) {
    const float* x   = (const float*)d_in[0];
    const int*   ei  = (const int*)d_in[1];
    const float* ewt = (const float*)d_in[2];
    const float* w1  = (const float*)d_in[3];
    const float* we1 = (const float*)d_in[4];
    const float* as1 = (const float*)d_in[5];
    const float* ad1 = (const float*)d_in[6];
    const float* ae1 = (const float*)d_in[7];
    const float* b1  = (const float*)d_in[8];
    const float* w2  = (const float*)d_in[9];
    const float* we2 = (const float*)d_in[10];
    const float* as2 = (const float*)d_in[11];
    const float* ad2 = (const float*)d_in[12];
    const float* ae2 = (const float*)d_in[13];
    const float* b2  = (const float*)d_in[14];

    const int N = in_sizes[0] / 64;
    const int E = in_sizes[1] / 2;
    const int Etot = E + N;
    const int* srcI = ei;
    const int* dstI = ei + E;
    const int nb = (N + SCAN_BS - 1) / SCAN_BS;

    char* base = (char*)d_ws;
    size_t off = 0;
    auto alloc = [&](size_t bytes) { char* p = base + off; off += (bytes + 15) & ~(size_t)15; return p; };
    float* xs     = (float*)alloc((size_t)N * 128 * sizeof(float));
    float* h1     = (float*)alloc((size_t)N * 32 * sizeof(float));
    float* asrc   = (float*)alloc((size_t)N * 4 * sizeof(float));
    float* adst   = (float*)alloc((size_t)N * 4 * sizeof(float));
    float* loopat = (float*)alloc((size_t)N * sizeof(float));
    float* sums   = (float*)alloc((size_t)N * sizeof(float));
    int*   cnt    = (int*)alloc((size_t)N * sizeof(int));
    int*   incl   = (int*)alloc((size_t)N * sizeof(int));
    int*   bsum   = (int*)alloc(512 * sizeof(int));
    int*   rowptr = (int*)alloc((size_t)(N + 1) * sizeof(int));
    int*   fill   = (int*)alloc((size_t)N * sizeof(int));
    int*   esrc   = (int*)alloc((size_t)Etot * sizeof(int));
    float* eea    = (float*)alloc((size_t)Etot * sizeof(float));
    float* wedot  = (float*)alloc(8 * sizeof(float));

    float* outF = (float*)d_out;

    hipMemsetAsync(sums, 0, (size_t)N * sizeof(float), stream);
    hipMemsetAsync(cnt, 0, (size_t)N * sizeof(int), stream);
    hipMemsetAsync(fill, 0, (size_t)N * sizeof(int), stream);

    // CSR build + self-loop attrs
    k_deg<<<(E + 255) / 256, 256, 0, stream>>>(dstI, ewt, sums, cnt, E);
    k_loopfin<<<(N + 255) / 256, 256, 0, stream>>>(sums, cnt, loopat, N);
    k_wedot<<<1, 128, 0, stream>>>(we1, ae1, we2, ae2, wedot);
    k_scanA<<<nb, SCAN_BS, 0, stream>>>(cnt, incl, bsum, N);
    k_scanB<<<1, 512, 0, stream>>>(bsum, nb);
    k_scanC<<<nb, SCAN_BS, 0, stream>>>(cnt, incl, bsum, rowptr, N, Etot);
    k_scatter<<<(Etot + 255) / 256, 256, 0, stream>>>(srcI, dstI, ewt, loopat,
                                                      rowptr, fill, esrc, eea, E, Etot);

    const int gemmb = (N + 63) / 64;
    const int gb = (N + 3) / 4;

    // layer 1
    k_gemm1<<<gemmb, 256, 0, stream>>>(x, w1, as1, ad1, xs, asrc, adst, N);
    k_gather<<<gb, 256, 0, stream>>>(esrc, eea, rowptr, xs, asrc, adst,
                                     wedot + 0, b1, h1, N);

    // layer 2
    k_gemm2<<<gemmb, 256, 0, stream>>>(h1, w2, as2, ad2, xs, asrc, adst, N);
    k_gather<<<gb, 256, 0, stream>>>(esrc, eea, rowptr, xs, asrc, adst,
                                     wedot + 4, b2, outF, N);
}

// Round 9
// 538.194 us; speedup vs baseline: 3.7241x; 1.3226x over previous
//
#include <hip/hip_runtime.h>
#include <hip/hip_fp16.h>
#include <cstddef>

#define GAT_EPS 1e-16f
#define SCAN_BS 256

// ---- histogram (in-degree) + edge_weight sums for self-loop fill='mean' ----
__global__ void k_deg(const int* __restrict__ dst, const float* __restrict__ ew,
                      float* __restrict__ sums, int* __restrict__ cnt, int E) {
    int i = blockIdx.x * blockDim.x + threadIdx.x;
    if (i < E) {
        int d = dst[i];
        atomicAdd(&sums[d], ew[i]);
        atomicAdd(&cnt[d], 1);
    }
}

// ---- per-head edge-attr dot constants ----
__global__ void k_wedot(const float* __restrict__ we1, const float* __restrict__ ae1,
                        const float* __restrict__ we2, const float* __restrict__ ae2,
                        float* __restrict__ wd) {
    int t = threadIdx.x;  // 128
    float v1 = we1[t] * ae1[t];
    float v2 = we2[t] * ae2[t];
#pragma unroll
    for (int off = 16; off; off >>= 1) {
        v1 += __shfl_xor(v1, off);
        v2 += __shfl_xor(v2, off);
    }
    if ((t & 31) == 0) { wd[t >> 5] = v1; wd[4 + (t >> 5)] = v2; }
}

// ---- exclusive scan of (cnt[i]+1) -> rowptr; also finalizes loop attrs ----
__global__ void k_scanA(const int* __restrict__ cnt, const float* __restrict__ sums,
                        float* __restrict__ loopat, int* __restrict__ incl,
                        int* __restrict__ bsum, int N) {
    __shared__ int sh[SCAN_BS];
    int i = blockIdx.x * SCAN_BS + threadIdx.x;
    int cv = (i < N) ? cnt[i] : 0;
    if (i < N) loopat[i] = sums[i] / fmaxf((float)cv, 1.0f);
    int v = (i < N) ? cv + 1 : 0;
    sh[threadIdx.x] = v;
    __syncthreads();
    for (int off = 1; off < SCAN_BS; off <<= 1) {
        int t = (threadIdx.x >= off) ? sh[threadIdx.x - off] : 0;
        __syncthreads();
        sh[threadIdx.x] += t;
        __syncthreads();
    }
    if (i < N) incl[i] = sh[threadIdx.x];
    if (threadIdx.x == SCAN_BS - 1) bsum[blockIdx.x] = sh[threadIdx.x];
}

__global__ void k_scanB(int* __restrict__ bsum, int nb) {
    __shared__ int sh[512];
    int t = threadIdx.x;
    int v = (t < nb) ? bsum[t] : 0;
    sh[t] = v;
    __syncthreads();
    for (int off = 1; off < 512; off <<= 1) {
        int u = (t >= off) ? sh[t - off] : 0;
        __syncthreads();
        sh[t] += u;
        __syncthreads();
    }
    if (t < nb) bsum[t] = sh[t] - v;
}

__global__ void k_scanC(const int* __restrict__ cnt, const int* __restrict__ incl,
                        const int* __restrict__ bsum, int* __restrict__ rowptr,
                        int N, int Etot) {
    int i = blockIdx.x * SCAN_BS + threadIdx.x;
    if (i < N) rowptr[i] = bsum[blockIdx.x] + incl[i] - (cnt[i] + 1);
    if (i == N - 1) rowptr[N] = Etot;
}

// ---- scatter edges into CSR segments; (src, ea) packed as int2 ----
__global__ void k_scatter(const int* __restrict__ src, const int* __restrict__ dst,
                          const float* __restrict__ ew, const float* __restrict__ loopat,
                          const int* __restrict__ rowptr, int* __restrict__ fill,
                          int2* __restrict__ epk, int E, int Etot) {
    int e = blockIdx.x * blockDim.x + threadIdx.x;
    if (e >= Etot) return;
    int s, d; float ea;
    if (e < E) { s = src[e]; d = dst[e]; ea = ew[e]; }
    else       { s = e - E; d = s;       ea = loopat[s]; }
    int pos = rowptr[d] + atomicAdd(&fill[d], 1);
    int2 pk; pk.x = s; pk.y = __float_as_int(ea);
    epk[pos] = pk;
}

// ---- layer-1 GEMM + fused attn dots: xs = x @ W1^T (K=64), xs stored fp16. ----
__global__ __launch_bounds__(256, 2)
void k_gemm1(const float* __restrict__ x, const float* __restrict__ W,
             const float* __restrict__ as_, const float* __restrict__ ad_,
             __half* __restrict__ xs, float* __restrict__ asrc,
             float* __restrict__ adst, int N) {
    int n0 = blockIdx.x * 64;
    int t = threadIdx.x;          // 256
    int tx = t & 31;              // col lane
    int ty = t >> 5;              // row group 0..7
    __shared__ float Wsh[128 * 65];
    __shared__ float xsh[64 * 65];
    int nrows = min(64, N - n0);
    for (int j = t; j < 8192; j += 256) Wsh[(j >> 6) * 65 + (j & 63)] = W[j];
    const float* xg = x + (size_t)n0 * 64;
    for (int j = t; j < nrows * 64; j += 256) xsh[(j >> 6) * 65 + (j & 63)] = xg[j];
    __syncthreads();

    float acc[8][4];
#pragma unroll
    for (int i = 0; i < 8; i++)
#pragma unroll
        for (int j = 0; j < 4; j++) acc[i][j] = 0.f;

#pragma unroll 4
    for (int k = 0; k < 64; k++) {
        float w0 = Wsh[(tx     ) * 65 + k];
        float w1 = Wsh[(tx + 32) * 65 + k];
        float w2 = Wsh[(tx + 64) * 65 + k];
        float w3 = Wsh[(tx + 96) * 65 + k];
#pragma unroll
        for (int i = 0; i < 8; i++) {
            float xv = xsh[(ty * 8 + i) * 65 + k];
            acc[i][0] += xv * w0;
            acc[i][1] += xv * w1;
            acc[i][2] += xv * w2;
            acc[i][3] += xv * w3;
        }
    }

    float asv[4], adv[4];
#pragma unroll
    for (int j = 0; j < 4; j++) { asv[j] = as_[32 * j + tx]; adv[j] = ad_[32 * j + tx]; }

#pragma unroll
    for (int i = 0; i < 8; i++) {
        int row = ty * 8 + i;
        bool ok = row < nrows;
        __half* orow = xs + (size_t)(n0 + row) * 128;
#pragma unroll
        for (int j = 0; j < 4; j++) {
            if (ok) orow[32 * j + tx] = __float2half(acc[i][j]);
            float vs = acc[i][j] * asv[j];
            float vd = acc[i][j] * adv[j];
#pragma unroll
            for (int off = 16; off; off >>= 1) {
                vs += __shfl_xor(vs, off);
                vd += __shfl_xor(vd, off);
            }
            if (ok && tx == 0) {
                asrc[(size_t)(n0 + row) * 4 + j] = vs;
                adst[(size_t)(n0 + row) * 4 + j] = vd;
            }
        }
    }
}

// ---- layer-2 GEMM + fused attn dots: xs = h1 @ W2^T (K=32), xs fp16. ----
__global__ __launch_bounds__(256, 2)
void k_gemm2(const float* __restrict__ h1, const float* __restrict__ W2,
             const float* __restrict__ as_, const float* __restrict__ ad_,
             __half* __restrict__ xs, float* __restrict__ asrc,
             float* __restrict__ adst, int N) {
    int n0 = blockIdx.x * 64;
    int t = threadIdx.x;
    int tx = t & 31;
    int ty = t >> 5;
    __shared__ float Wsh[128 * 33];
    __shared__ float xsh[64 * 33];
    int nrows = min(64, N - n0);
    for (int j = t; j < 4096; j += 256) Wsh[(j >> 5) * 33 + (j & 31)] = W2[j];
    const float* xg = h1 + (size_t)n0 * 32;
    for (int j = t; j < nrows * 32; j += 256) xsh[(j >> 5) * 33 + (j & 31)] = xg[j];
    __syncthreads();

    float acc[8][4];
#pragma unroll
    for (int i = 0; i < 8; i++)
#pragma unroll
        for (int j = 0; j < 4; j++) acc[i][j] = 0.f;

#pragma unroll 4
    for (int k = 0; k < 32; k++) {
        float w0 = Wsh[(tx     ) * 33 + k];
        float w1 = Wsh[(tx + 32) * 33 + k];
        float w2 = Wsh[(tx + 64) * 33 + k];
        float w3 = Wsh[(tx + 96) * 33 + k];
#pragma unroll
        for (int i = 0; i < 8; i++) {
            float xv = xsh[(ty * 8 + i) * 33 + k];
            acc[i][0] += xv * w0;
            acc[i][1] += xv * w1;
            acc[i][2] += xv * w2;
            acc[i][3] += xv * w3;
        }
    }

    float asv[4], adv[4];
#pragma unroll
    for (int j = 0; j < 4; j++) { asv[j] = as_[32 * j + tx]; adv[j] = ad_[32 * j + tx]; }

#pragma unroll
    for (int i = 0; i < 8; i++) {
        int row = ty * 8 + i;
        bool ok = row < nrows;
        __half* orow = xs + (size_t)(n0 + row) * 128;
#pragma unroll
        for (int j = 0; j < 4; j++) {
            if (ok) orow[32 * j + tx] = __float2half(acc[i][j]);
            float vs = acc[i][j] * asv[j];
            float vd = acc[i][j] * adv[j];
#pragma unroll
            for (int off = 16; off; off >>= 1) {
                vs += __shfl_xor(vs, off);
                vd += __shfl_xor(vd, off);
            }
            if (ok && tx == 0) {
                asrc[(size_t)(n0 + row) * 4 + j] = vs;
                adst[(size_t)(n0 + row) * 4 + j] = vd;
            }
        }
    }
}

// ---- fused gather: softmax-weighted aggregation + head-mean + bias + relu.
//      One 64-lane wave per node, 4 edges per loop iteration, fp16 rows. ----
__global__ void k_gather(const int2* __restrict__ epk, const int* __restrict__ rowptr,
                         const __half2* __restrict__ xs2,
                         const float* __restrict__ asrc, const float* __restrict__ adst,
                         const float* __restrict__ wedot, const float* __restrict__ bias,
                         float* __restrict__ out, int N) {
    int node = blockIdx.x * (blockDim.x >> 6) + (threadIdx.x >> 6);
    if (node >= N) return;
    int l = threadIdx.x & 63;
    int h = l >> 4;
    float wd = wedot[h];
    float ad = adst[(size_t)node * 4 + h];
    int beg = rowptr[node], end = rowptr[node + 1];

    float a0 = 0.f, a1 = 0.f, ds = 0.f;
    int i = beg;
    for (; i + 3 < end; i += 4) {
        int2 pA = epk[i], pB = epk[i + 1], pC = epk[i + 2], pD = epk[i + 3];
        float asA = asrc[(size_t)pA.x * 4 + h];
        float asB = asrc[(size_t)pB.x * 4 + h];
        float asC = asrc[(size_t)pC.x * 4 + h];
        float asD = asrc[(size_t)pD.x * 4 + h];
        __half2 vA = xs2[(size_t)pA.x * 64 + l];
        __half2 vB = xs2[(size_t)pB.x * 64 + l];
        __half2 vC = xs2[(size_t)pC.x * 64 + l];
        __half2 vD = xs2[(size_t)pD.x * 64 + l];
        float alA = asA + ad + __int_as_float(pA.y) * wd;
        float alB = asB + ad + __int_as_float(pB.y) * wd;
        float alC = asC + ad + __int_as_float(pC.y) * wd;
        float alD = asD + ad + __int_as_float(pD.y) * wd;
        alA = alA > 0.f ? alA : 0.2f * alA;
        alB = alB > 0.f ? alB : 0.2f * alB;
        alC = alC > 0.f ? alC : 0.2f * alC;
        alD = alD > 0.f ? alD : 0.2f * alD;
        float wA = __expf(alA), wB = __expf(alB), wC = __expf(alC), wD = __expf(alD);
        float2 fA = __half22float2(vA);
        float2 fB = __half22float2(vB);
        float2 fC = __half22float2(vC);
        float2 fD = __half22float2(vD);
        a0 += wA * fA.x + wB * fB.x + wC * fC.x + wD * fD.x;
        a1 += wA * fA.y + wB * fB.y + wC * fC.y + wD * fD.y;
        ds += wA + wB + wC + wD;
    }
    for (; i < end; ++i) {
        int2 p = epk[i];
        float as = asrc[(size_t)p.x * 4 + h];
        __half2 v = xs2[(size_t)p.x * 64 + l];
        float al = as + ad + __int_as_float(p.y) * wd;
        al = al > 0.f ? al : 0.2f * al;
        float w = __expf(al);
        float2 f = __half22float2(v);
        a0 += w * f.x;
        a1 += w * f.y;
        ds += w;
    }
    float inv = 1.f / (ds + GAT_EPS);
    a0 *= inv; a1 *= inv;
    a0 += __shfl_xor(a0, 16);
    a1 += __shfl_xor(a1, 16);
    a0 += __shfl_xor(a0, 32);
    a1 += __shfl_xor(a1, 32);
    if (l < 16) {
        int c0 = 2 * l;
        float r0 = fmaxf(0.25f * a0 + bias[c0], 0.f);
        float r1 = fmaxf(0.25f * a1 + bias[c0 + 1], 0.f);
        reinterpret_cast<float2*>(out)[(size_t)node * 16 + l] = make_float2(r0, r1);
    }
}

extern "C" void kernel_launch(void* const* d_in, const int* in_sizes, int n_in,
                              void* d_out, int out_size, void* d_ws, size_t ws_size,
                              hipStream_t stream) {
    const float* x   = (const float*)d_in[0];
    const int*   ei  = (const int*)d_in[1];
    const float* ewt = (const float*)d_in[2];
    const float* w1  = (const float*)d_in[3];
    const float* we1 = (const float*)d_in[4];
    const float* as1 = (const float*)d_in[5];
    const float* ad1 = (const float*)d_in[6];
    const float* ae1 = (const float*)d_in[7];
    const float* b1  = (const float*)d_in[8];
    const float* w2  = (const float*)d_in[9];
    const float* we2 = (const float*)d_in[10];
    const float* as2 = (const float*)d_in[11];
    const float* ad2 = (const float*)d_in[12];
    const float* ae2 = (const float*)d_in[13];
    const float* b2  = (const float*)d_in[14];

    const int N = in_sizes[0] / 64;
    const int E = in_sizes[1] / 2;
    const int Etot = E + N;
    const int* srcI = ei;
    const int* dstI = ei + E;
    const int nb = (N + SCAN_BS - 1) / SCAN_BS;

    char* base = (char*)d_ws;
    size_t off = 0;
    auto alloc = [&](size_t bytes) { char* p = base + off; off += (bytes + 15) & ~(size_t)15; return p; };
    __half* xs    = (__half*)alloc((size_t)N * 128 * sizeof(__half));
    float* h1     = (float*)alloc((size_t)N * 32 * sizeof(float));
    float* asrc   = (float*)alloc((size_t)N * 4 * sizeof(float));
    float* adst   = (float*)alloc((size_t)N * 4 * sizeof(float));
    float* loopat = (float*)alloc((size_t)N * sizeof(float));
    float* sums   = (float*)alloc((size_t)N * sizeof(float));
    int*   cnt    = (int*)alloc((size_t)N * sizeof(int));
    int*   incl   = (int*)alloc((size_t)N * sizeof(int));
    int*   bsum   = (int*)alloc(512 * sizeof(int));
    int*   rowptr = (int*)alloc((size_t)(N + 1) * sizeof(int));
    int*   fill   = (int*)alloc((size_t)N * sizeof(int));
    int2*  epk    = (int2*)alloc((size_t)Etot * sizeof(int2));
    float* wedot  = (float*)alloc(8 * sizeof(float));

    float* outF = (float*)d_out;

    hipMemsetAsync(sums, 0, (size_t)N * sizeof(float), stream);
    hipMemsetAsync(cnt, 0, (size_t)N * sizeof(int), stream);
    hipMemsetAsync(fill, 0, (size_t)N * sizeof(int), stream);

    // CSR build + self-loop attrs
    k_deg<<<(E + 255) / 256, 256, 0, stream>>>(dstI, ewt, sums, cnt, E);
    k_wedot<<<1, 128, 0, stream>>>(we1, ae1, we2, ae2, wedot);
    k_scanA<<<nb, SCAN_BS, 0, stream>>>(cnt, sums, loopat, incl, bsum, N);
    k_scanB<<<1, 512, 0, stream>>>(bsum, nb);
    k_scanC<<<nb, SCAN_BS, 0, stream>>>(cnt, incl, bsum, rowptr, N, Etot);
    k_scatter<<<(Etot + 255) / 256, 256, 0, stream>>>(srcI, dstI, ewt, loopat,
                                                      rowptr, fill, epk, E, Etot);

    const int gemmb = (N + 63) / 64;
    const int gb = (N + 3) / 4;

    // layer 1
    k_gemm1<<<gemmb, 256, 0, stream>>>(x, w1, as1, ad1, xs, asrc, adst, N);
    k_gather<<<gb, 256, 0, stream>>>(epk, rowptr, (const __half2*)xs, asrc, adst,
                                     wedot + 0, b1, h1, N);

    // layer 2
    k_gemm2<<<gemmb, 256, 0, stream>>>(h1, w2, as2, ad2, xs, asrc, adst, N);
    k_gather<<<gb, 256, 0, stream>>>(epk, rowptr, (const __half2*)xs, asrc, adst,
                                     wedot + 4, b2, outF, N);
}

// Round 10
// 394.724 us; speedup vs baseline: 5.0777x; 1.3635x over previous
//
#include <hip/hip_runtime.h>
#include <hip/hip_fp16.h>
#include <cstddef>

#define GAT_EPS 1e-16f
#define SCAN_BS 256

// ---- fused histogram: one u64 atomic per edge gives (count | ew-sum) and
//      returns this edge's stable slot within its dst segment ----
__global__ void k_hist(const int* __restrict__ dst, const float* __restrict__ ew,
                       unsigned long long* __restrict__ pk, int* __restrict__ pos, int E) {
    int i = blockIdx.x * blockDim.x + threadIdx.x;
    if (i < E) {
        int d = dst[i];
        unsigned long long add = (1ULL << 44) |
            (unsigned long long)(ew[i] * 16777216.0f + 0.5f);
        unsigned long long old = atomicAdd(&pk[d], add);
        pos[i] = (int)(old >> 44);
    }
}

// ---- per-head edge-attr dot constants ----
__global__ void k_wedot(const float* __restrict__ we1, const float* __restrict__ ae1,
                        const float* __restrict__ we2, const float* __restrict__ ae2,
                        float* __restrict__ wd) {
    int t = threadIdx.x;  // 128
    float v1 = we1[t] * ae1[t];
    float v2 = we2[t] * ae2[t];
#pragma unroll
    for (int off = 16; off; off >>= 1) {
        v1 += __shfl_xor(v1, off);
        v2 += __shfl_xor(v2, off);
    }
    if ((t & 31) == 0) { wd[t >> 5] = v1; wd[4 + (t >> 5)] = v2; }
}

// ---- decode pk -> cnt/loopat; exclusive scan of (cnt+1) part A ----
__global__ void k_scanA(const unsigned long long* __restrict__ pk,
                        float* __restrict__ loopat, int* __restrict__ cnt,
                        int* __restrict__ incl, int* __restrict__ bsum, int N) {
    __shared__ int sh[SCAN_BS];
    int i = blockIdx.x * SCAN_BS + threadIdx.x;
    int cv = 0;
    if (i < N) {
        unsigned long long v = pk[i];
        cv = (int)(v >> 44);
        float sum = (float)(v & ((1ULL << 44) - 1)) * (1.0f / 16777216.0f);
        loopat[i] = sum / fmaxf((float)cv, 1.0f);
        cnt[i] = cv;
    }
    int v = (i < N) ? cv + 1 : 0;
    sh[threadIdx.x] = v;
    __syncthreads();
    for (int off = 1; off < SCAN_BS; off <<= 1) {
        int t = (threadIdx.x >= off) ? sh[threadIdx.x - off] : 0;
        __syncthreads();
        sh[threadIdx.x] += t;
        __syncthreads();
    }
    if (i < N) incl[i] = sh[threadIdx.x];
    if (threadIdx.x == SCAN_BS - 1) bsum[blockIdx.x] = sh[threadIdx.x];
}

__global__ void k_scanB(int* __restrict__ bsum, int nb) {
    __shared__ int sh[512];
    int t = threadIdx.x;
    int v = (t < nb) ? bsum[t] : 0;
    sh[t] = v;
    __syncthreads();
    for (int off = 1; off < 512; off <<= 1) {
        int u = (t >= off) ? sh[t - off] : 0;
        __syncthreads();
        sh[t] += u;
        __syncthreads();
    }
    if (t < nb) bsum[t] = sh[t] - v;
}

__global__ void k_scanC(const int* __restrict__ cnt, const int* __restrict__ incl,
                        const int* __restrict__ bsum, int* __restrict__ rowptr,
                        int N, int Etot) {
    int i = blockIdx.x * SCAN_BS + threadIdx.x;
    if (i < N) rowptr[i] = bsum[blockIdx.x] + incl[i] - (cnt[i] + 1);
    if (i == N - 1) rowptr[N] = Etot;
}

// ---- scatter edges into CSR segments, atomic-free (slots precomputed) ----
__global__ void k_scatter(const int* __restrict__ src, const int* __restrict__ dst,
                          const float* __restrict__ ew, const float* __restrict__ loopat,
                          const int* __restrict__ cnt, const int* __restrict__ pos,
                          const int* __restrict__ rowptr, int2* __restrict__ epk,
                          int E, int Etot) {
    int e = blockIdx.x * blockDim.x + threadIdx.x;
    if (e >= Etot) return;
    int s, d, p; float ea;
    if (e < E) { s = src[e]; d = dst[e]; ea = ew[e]; p = pos[e]; }
    else       { s = e - E; d = s;       ea = loopat[s]; p = cnt[d]; }
    int2 q; q.x = s; q.y = __float_as_int(ea);
    epk[rowptr[d] + p] = q;
}

// ---- layer-1 GEMM + fused attn dots: xs = x @ W1^T (K=64), xs stored fp16. ----
__global__ __launch_bounds__(256, 2)
void k_gemm1(const float* __restrict__ x, const float* __restrict__ W,
             const float* __restrict__ as_, const float* __restrict__ ad_,
             __half* __restrict__ xs, float* __restrict__ asrc,
             float* __restrict__ adst, int N) {
    int n0 = blockIdx.x * 64;
    int t = threadIdx.x;          // 256
    int tx = t & 31;              // col lane
    int ty = t >> 5;              // row group 0..7
    __shared__ float Wsh[128 * 65];
    __shared__ float xsh[64 * 65];
    int nrows = min(64, N - n0);
    for (int j = t; j < 8192; j += 256) Wsh[(j >> 6) * 65 + (j & 63)] = W[j];
    const float* xg = x + (size_t)n0 * 64;
    for (int j = t; j < nrows * 64; j += 256) xsh[(j >> 6) * 65 + (j & 63)] = xg[j];
    __syncthreads();

    float acc[8][4];
#pragma unroll
    for (int i = 0; i < 8; i++)
#pragma unroll
        for (int j = 0; j < 4; j++) acc[i][j] = 0.f;

#pragma unroll 4
    for (int k = 0; k < 64; k++) {
        float w0 = Wsh[(tx     ) * 65 + k];
        float w1 = Wsh[(tx + 32) * 65 + k];
        float w2 = Wsh[(tx + 64) * 65 + k];
        float w3 = Wsh[(tx + 96) * 65 + k];
#pragma unroll
        for (int i = 0; i < 8; i++) {
            float xv = xsh[(ty * 8 + i) * 65 + k];
            acc[i][0] += xv * w0;
            acc[i][1] += xv * w1;
            acc[i][2] += xv * w2;
            acc[i][3] += xv * w3;
        }
    }

    float asv[4], adv[4];
#pragma unroll
    for (int j = 0; j < 4; j++) { asv[j] = as_[32 * j + tx]; adv[j] = ad_[32 * j + tx]; }

#pragma unroll
    for (int i = 0; i < 8; i++) {
        int row = ty * 8 + i;
        bool ok = row < nrows;
        __half* orow = xs + (size_t)(n0 + row) * 128;
#pragma unroll
        for (int j = 0; j < 4; j++) {
            if (ok) orow[32 * j + tx] = __float2half(acc[i][j]);
            float vs = acc[i][j] * asv[j];
            float vd = acc[i][j] * adv[j];
#pragma unroll
            for (int off = 16; off; off >>= 1) {
                vs += __shfl_xor(vs, off);
                vd += __shfl_xor(vd, off);
            }
            if (ok && tx == 0) {
                asrc[(size_t)(n0 + row) * 4 + j] = vs;
                adst[(size_t)(n0 + row) * 4 + j] = vd;
            }
        }
    }
}

// ---- layer-2 GEMM + fused attn dots: xs = h1 @ W2^T (K=32), xs fp16. ----
__global__ __launch_bounds__(256, 2)
void k_gemm2(const float* __restrict__ h1, const float* __restrict__ W2,
             const float* __restrict__ as_, const float* __restrict__ ad_,
             __half* __restrict__ xs, float* __restrict__ asrc,
             float* __restrict__ adst, int N) {
    int n0 = blockIdx.x * 64;
    int t = threadIdx.x;
    int tx = t & 31;
    int ty = t >> 5;
    __shared__ float Wsh[128 * 33];
    __shared__ float xsh[64 * 33];
    int nrows = min(64, N - n0);
    for (int j = t; j < 4096; j += 256) Wsh[(j >> 5) * 33 + (j & 31)] = W2[j];
    const float* xg = h1 + (size_t)n0 * 32;
    for (int j = t; j < nrows * 32; j += 256) xsh[(j >> 5) * 33 + (j & 31)] = xg[j];
    __syncthreads();

    float acc[8][4];
#pragma unroll
    for (int i = 0; i < 8; i++)
#pragma unroll
        for (int j = 0; j < 4; j++) acc[i][j] = 0.f;

#pragma unroll 4
    for (int k = 0; k < 32; k++) {
        float w0 = Wsh[(tx     ) * 33 + k];
        float w1 = Wsh[(tx + 32) * 33 + k];
        float w2 = Wsh[(tx + 64) * 33 + k];
        float w3 = Wsh[(tx + 96) * 33 + k];
#pragma unroll
        for (int i = 0; i < 8; i++) {
            float xv = xsh[(ty * 8 + i) * 33 + k];
            acc[i][0] += xv * w0;
            acc[i][1] += xv * w1;
            acc[i][2] += xv * w2;
            acc[i][3] += xv * w3;
        }
    }

    float asv[4], adv[4];
#pragma unroll
    for (int j = 0; j < 4; j++) { asv[j] = as_[32 * j + tx]; adv[j] = ad_[32 * j + tx]; }

#pragma unroll
    for (int i = 0; i < 8; i++) {
        int row = ty * 8 + i;
        bool ok = row < nrows;
        __half* orow = xs + (size_t)(n0 + row) * 128;
#pragma unroll
        for (int j = 0; j < 4; j++) {
            if (ok) orow[32 * j + tx] = __float2half(acc[i][j]);
            float vs = acc[i][j] * asv[j];
            float vd = acc[i][j] * adv[j];
#pragma unroll
            for (int off = 16; off; off >>= 1) {
                vs += __shfl_xor(vs, off);
                vd += __shfl_xor(vd, off);
            }
            if (ok && tx == 0) {
                asrc[(size_t)(n0 + row) * 4 + j] = vs;
                adst[(size_t)(n0 + row) * 4 + j] = vd;
            }
        }
    }
}

// ---- fused gather: softmax-weighted aggregation + head-mean + bias + relu.
//      One 64-lane wave per node, 4 edges per loop iteration, fp16 rows. ----
__global__ void k_gather(const int2* __restrict__ epk, const int* __restrict__ rowptr,
                         const __half2* __restrict__ xs2,
                         const float* __restrict__ asrc, const float* __restrict__ adst,
                         const float* __restrict__ wedot, const float* __restrict__ bias,
                         float* __restrict__ out, int N) {
    int node = blockIdx.x * (blockDim.x >> 6) + (threadIdx.x >> 6);
    if (node >= N) return;
    int l = threadIdx.x & 63;
    int h = l >> 4;
    float wd = wedot[h];
    float ad = adst[(size_t)node * 4 + h];
    int beg = rowptr[node], end = rowptr[node + 1];

    float a0 = 0.f, a1 = 0.f, ds = 0.f;
    int i = beg;
    for (; i + 3 < end; i += 4) {
        int2 pA = epk[i], pB = epk[i + 1], pC = epk[i + 2], pD = epk[i + 3];
        float asA = asrc[(size_t)pA.x * 4 + h];
        float asB = asrc[(size_t)pB.x * 4 + h];
        float asC = asrc[(size_t)pC.x * 4 + h];
        float asD = asrc[(size_t)pD.x * 4 + h];
        __half2 vA = xs2[(size_t)pA.x * 64 + l];
        __half2 vB = xs2[(size_t)pB.x * 64 + l];
        __half2 vC = xs2[(size_t)pC.x * 64 + l];
        __half2 vD = xs2[(size_t)pD.x * 64 + l];
        float alA = asA + ad + __int_as_float(pA.y) * wd;
        float alB = asB + ad + __int_as_float(pB.y) * wd;
        float alC = asC + ad + __int_as_float(pC.y) * wd;
        float alD = asD + ad + __int_as_float(pD.y) * wd;
        alA = alA > 0.f ? alA : 0.2f * alA;
        alB = alB > 0.f ? alB : 0.2f * alB;
        alC = alC > 0.f ? alC : 0.2f * alC;
        alD = alD > 0.f ? alD : 0.2f * alD;
        float wA = __expf(alA), wB = __expf(alB), wC = __expf(alC), wD = __expf(alD);
        float2 fA = __half22float2(vA);
        float2 fB = __half22float2(vB);
        float2 fC = __half22float2(vC);
        float2 fD = __half22float2(vD);
        a0 += wA * fA.x + wB * fB.x + wC * fC.x + wD * fD.x;
        a1 += wA * fA.y + wB * fB.y + wC * fC.y + wD * fD.y;
        ds += wA + wB + wC + wD;
    }
    for (; i < end; ++i) {
        int2 p = epk[i];
        float as = asrc[(size_t)p.x * 4 + h];
        __half2 v = xs2[(size_t)p.x * 64 + l];
        float al = as + ad + __int_as_float(p.y) * wd;
        al = al > 0.f ? al : 0.2f * al;
        float w = __expf(al);
        float2 f = __half22float2(v);
        a0 += w * f.x;
        a1 += w * f.y;
        ds += w;
    }
    float inv = 1.f / (ds + GAT_EPS);
    a0 *= inv; a1 *= inv;
    a0 += __shfl_xor(a0, 16);
    a1 += __shfl_xor(a1, 16);
    a0 += __shfl_xor(a0, 32);
    a1 += __shfl_xor(a1, 32);
    if (l < 16) {
        int c0 = 2 * l;
        float r0 = fmaxf(0.25f * a0 + bias[c0], 0.f);
        float r1 = fmaxf(0.25f * a1 + bias[c0 + 1], 0.f);
        reinterpret_cast<float2*>(out)[(size_t)node * 16 + l] = make_float2(r0, r1);
    }
}

extern "C" void kernel_launch(void* const* d_in, const int* in_sizes, int n_in,
                              void* d_out, int out_size, void* d_ws, size_t ws_size,
                              hipStream_t stream) {
    const float* x   = (const float*)d_in[0];
    const int*   ei  = (const int*)d_in[1];
    const float* ewt = (const float*)d_in[2];
    const float* w1  = (const float*)d_in[3];
    const float* we1 = (const float*)d_in[4];
    const float* as1 = (const float*)d_in[5];
    const float* ad1 = (const float*)d_in[6];
    const float* ae1 = (const float*)d_in[7];
    const float* b1  = (const float*)d_in[8];
    const float* w2  = (const float*)d_in[9];
    const float* we2 = (const float*)d_in[10];
    const float* as2 = (const float*)d_in[11];
    const float* ad2 = (const float*)d_in[12];
    const float* ae2 = (const float*)d_in[13];
    const float* b2  = (const float*)d_in[14];

    const int N = in_sizes[0] / 64;
    const int E = in_sizes[1] / 2;
    const int Etot = E + N;
    const int* srcI = ei;
    const int* dstI = ei + E;
    const int nb = (N + SCAN_BS - 1) / SCAN_BS;

    char* base = (char*)d_ws;
    size_t off = 0;
    auto alloc = [&](size_t bytes) { char* p = base + off; off += (bytes + 15) & ~(size_t)15; return p; };
    __half* xs    = (__half*)alloc((size_t)N * 128 * sizeof(__half));
    float* h1     = (float*)alloc((size_t)N * 32 * sizeof(float));
    float* asrc   = (float*)alloc((size_t)N * 4 * sizeof(float));
    float* adst   = (float*)alloc((size_t)N * 4 * sizeof(float));
    float* loopat = (float*)alloc((size_t)N * sizeof(float));
    unsigned long long* pk = (unsigned long long*)alloc((size_t)N * sizeof(unsigned long long));
    int*   cnt    = (int*)alloc((size_t)N * sizeof(int));
    int*   incl   = (int*)alloc((size_t)N * sizeof(int));
    int*   bsum   = (int*)alloc(512 * sizeof(int));
    int*   rowptr = (int*)alloc((size_t)(N + 1) * sizeof(int));
    int*   pos    = (int*)alloc((size_t)E * sizeof(int));
    int2*  epk    = (int2*)alloc((size_t)Etot * sizeof(int2));
    float* wedot  = (float*)alloc(8 * sizeof(float));

    float* outF = (float*)d_out;

    hipMemsetAsync(pk, 0, (size_t)N * sizeof(unsigned long long), stream);

    // CSR build + self-loop attrs (one u64 atomic per edge, triple duty)
    k_hist<<<(E + 255) / 256, 256, 0, stream>>>(dstI, ewt, pk, pos, E);
    k_wedot<<<1, 128, 0, stream>>>(we1, ae1, we2, ae2, wedot);
    k_scanA<<<nb, SCAN_BS, 0, stream>>>(pk, loopat, cnt, incl, bsum, N);
    k_scanB<<<1, 512, 0, stream>>>(bsum, nb);
    k_scanC<<<nb, SCAN_BS, 0, stream>>>(cnt, incl, bsum, rowptr, N, Etot);
    k_scatter<<<(Etot + 255) / 256, 256, 0, stream>>>(srcI, dstI, ewt, loopat,
                                                      cnt, pos, rowptr, epk, E, Etot);

    const int gemmb = (N + 63) / 64;
    const int gb = (N + 3) / 4;

    // layer 1
    k_gemm1<<<gemmb, 256, 0, stream>>>(x, w1, as1, ad1, xs, asrc, adst, N);
    k_gather<<<gb, 256, 0, stream>>>(epk, rowptr, (const __half2*)xs, asrc, adst,
                                     wedot + 0, b1, h1, N);

    // layer 2
    k_gemm2<<<gemmb, 256, 0, stream>>>(h1, w2, as2, ad2, xs, asrc, adst, N);
    k_gather<<<gb, 256, 0, stream>>>(epk, rowptr, (const __half2*)xs, asrc, adst,
                                     wedot + 4, b2, outF, N);
}

// Round 11
// 337.783 us; speedup vs baseline: 5.9336x; 1.1686x over previous
//
#include <hip/hip_runtime.h>
#include <hip/hip_fp16.h>
#include <cstddef>

#define GAT_EPS 1e-16f
#define SCAN_BS 256

// ---- decode pk -> cnt/loopat; exclusive scan of (cnt+1) part A ----
__global__ void k_scanA(const unsigned long long* __restrict__ pk,
                        float* __restrict__ loopat, int* __restrict__ cnt,
                        int* __restrict__ incl, int* __restrict__ bsum, int N) {
    __shared__ int sh[SCAN_BS];
    int i = blockIdx.x * SCAN_BS + threadIdx.x;
    int cv = 0;
    if (i < N) {
        unsigned long long v = pk[i];
        cv = (int)(v >> 44);
        float sum = (float)(v & ((1ULL << 44) - 1)) * (1.0f / 16777216.0f);
        loopat[i] = sum / fmaxf((float)cv, 1.0f);
        cnt[i] = cv;
    }
    int v = (i < N) ? cv + 1 : 0;
    sh[threadIdx.x] = v;
    __syncthreads();
    for (int off = 1; off < SCAN_BS; off <<= 1) {
        int t = (threadIdx.x >= off) ? sh[threadIdx.x - off] : 0;
        __syncthreads();
        sh[threadIdx.x] += t;
        __syncthreads();
    }
    if (i < N) incl[i] = sh[threadIdx.x];
    if (threadIdx.x == SCAN_BS - 1) bsum[blockIdx.x] = sh[threadIdx.x];
}

// ---- scan part B (single block) + folded wedot computation ----
__global__ void k_scanB(int* __restrict__ bsum, int nb,
                        const float* __restrict__ we1, const float* __restrict__ ae1,
                        const float* __restrict__ we2, const float* __restrict__ ae2,
                        float* __restrict__ wd) {
    int t = threadIdx.x;
    if (t < 128) {
        float v1 = we1[t] * ae1[t];
        float v2 = we2[t] * ae2[t];
#pragma unroll
        for (int off = 16; off; off >>= 1) {
            v1 += __shfl_xor(v1, off);
            v2 += __shfl_xor(v2, off);
        }
        if ((t & 31) == 0) { wd[t >> 5] = v1; wd[4 + (t >> 5)] = v2; }
    }
    __shared__ int sh[512];
    int v = (t < nb) ? bsum[t] : 0;
    sh[t] = v;
    __syncthreads();
    for (int off = 1; off < 512; off <<= 1) {
        int u = (t >= off) ? sh[t - off] : 0;
        __syncthreads();
        sh[t] += u;
        __syncthreads();
    }
    if (t < nb) bsum[t] = sh[t] - v;
}

__global__ void k_scanC(const int* __restrict__ cnt, const int* __restrict__ incl,
                        const int* __restrict__ bsum, int* __restrict__ rowptr,
                        int N, int Etot) {
    int i = blockIdx.x * SCAN_BS + threadIdx.x;
    if (i < N) rowptr[i] = bsum[blockIdx.x] + incl[i] - (cnt[i] + 1);
    if (i == N - 1) rowptr[N] = Etot;
}

// ---- scatter edges into CSR segments, atomic-free (slots precomputed) ----
__global__ void k_scatter(const int* __restrict__ src, const int* __restrict__ dst,
                          const float* __restrict__ ew, const float* __restrict__ loopat,
                          const int* __restrict__ cnt, const int* __restrict__ pos,
                          const int* __restrict__ rowptr, int2* __restrict__ epk,
                          int E, int Etot) {
    int e = blockIdx.x * blockDim.x + threadIdx.x;
    if (e >= Etot) return;
    int s, d, p; float ea;
    if (e < E) { s = src[e]; d = dst[e]; ea = ew[e]; p = pos[e]; }
    else       { s = e - E; d = s;       ea = loopat[s]; p = cnt[d]; }
    int2 q; q.x = s; q.y = __float_as_int(ea);
    epk[rowptr[d] + p] = q;
}

// ---- FUSED: layer-1 GEMM (+attn dots) AND edge histogram.
//      Interleaved block mapping: bx%5==0 -> gemm tile, else hist chunk.
//      Hist is atomic-latency-bound (idle VALU/LDS); gemm is VALU/LDS-bound. ----
__global__ __launch_bounds__(256, 2)
void k_gemm1h(const float* __restrict__ x, const float* __restrict__ W,
              const float* __restrict__ as_, const float* __restrict__ ad_,
              __half* __restrict__ xs, float* __restrict__ asrc,
              float* __restrict__ adst, int N, int gemmb,
              const int* __restrict__ dst, const float* __restrict__ ew,
              unsigned long long* __restrict__ pk, int* __restrict__ pos, int E) {
    int g = blockIdx.x / 5;
    int r = blockIdx.x % 5;
    if (r != 0) {
        int i = (g * 4 + r - 1) * 256 + threadIdx.x;
        if (i < E) {
            int d = dst[i];
            unsigned long long add = (1ULL << 44) |
                (unsigned long long)(ew[i] * 16777216.0f + 0.5f);
            unsigned long long old = atomicAdd(&pk[d], add);
            pos[i] = (int)(old >> 44);
        }
        return;
    }
    if (g >= gemmb) return;

    int n0 = g * 64;
    int t = threadIdx.x;          // 256
    int tx = t & 31;              // col lane
    int ty = t >> 5;              // row group 0..7
    __shared__ float Wsh[128 * 65];
    __shared__ float xsh[64 * 65];
    int nrows = min(64, N - n0);
    for (int j = t; j < 8192; j += 256) Wsh[(j >> 6) * 65 + (j & 63)] = W[j];
    const float* xg = x + (size_t)n0 * 64;
    for (int j = t; j < nrows * 64; j += 256) xsh[(j >> 6) * 65 + (j & 63)] = xg[j];
    __syncthreads();

    float acc[8][4];
#pragma unroll
    for (int i = 0; i < 8; i++)
#pragma unroll
        for (int j = 0; j < 4; j++) acc[i][j] = 0.f;

#pragma unroll 4
    for (int k = 0; k < 64; k++) {
        float w0 = Wsh[(tx     ) * 65 + k];
        float w1 = Wsh[(tx + 32) * 65 + k];
        float w2 = Wsh[(tx + 64) * 65 + k];
        float w3 = Wsh[(tx + 96) * 65 + k];
#pragma unroll
        for (int i = 0; i < 8; i++) {
            float xv = xsh[(ty * 8 + i) * 65 + k];
            acc[i][0] += xv * w0;
            acc[i][1] += xv * w1;
            acc[i][2] += xv * w2;
            acc[i][3] += xv * w3;
        }
    }

    float asv[4], adv[4];
#pragma unroll
    for (int j = 0; j < 4; j++) { asv[j] = as_[32 * j + tx]; adv[j] = ad_[32 * j + tx]; }

#pragma unroll
    for (int i = 0; i < 8; i++) {
        int row = ty * 8 + i;
        bool ok = row < nrows;
        __half* orow = xs + (size_t)(n0 + row) * 128;
#pragma unroll
        for (int j = 0; j < 4; j++) {
            if (ok) orow[32 * j + tx] = __float2half(acc[i][j]);
            float vs = acc[i][j] * asv[j];
            float vd = acc[i][j] * adv[j];
#pragma unroll
            for (int off = 16; off; off >>= 1) {
                vs += __shfl_xor(vs, off);
                vd += __shfl_xor(vd, off);
            }
            if (ok && tx == 0) {
                asrc[(size_t)(n0 + row) * 4 + j] = vs;
                adst[(size_t)(n0 + row) * 4 + j] = vd;
            }
        }
    }
}

// ---- layer-2 GEMM + fused attn dots: xs = h1 @ W2^T (K=32), xs fp16. ----
__global__ __launch_bounds__(256, 2)
void k_gemm2(const float* __restrict__ h1, const float* __restrict__ W2,
             const float* __restrict__ as_, const float* __restrict__ ad_,
             __half* __restrict__ xs, float* __restrict__ asrc,
             float* __restrict__ adst, int N) {
    int n0 = blockIdx.x * 64;
    int t = threadIdx.x;
    int tx = t & 31;
    int ty = t >> 5;
    __shared__ float Wsh[128 * 33];
    __shared__ float xsh[64 * 33];
    int nrows = min(64, N - n0);
    for (int j = t; j < 4096; j += 256) Wsh[(j >> 5) * 33 + (j & 31)] = W2[j];
    const float* xg = h1 + (size_t)n0 * 32;
    for (int j = t; j < nrows * 32; j += 256) xsh[(j >> 5) * 33 + (j & 31)] = xg[j];
    __syncthreads();

    float acc[8][4];
#pragma unroll
    for (int i = 0; i < 8; i++)
#pragma unroll
        for (int j = 0; j < 4; j++) acc[i][j] = 0.f;

#pragma unroll 4
    for (int k = 0; k < 32; k++) {
        float w0 = Wsh[(tx     ) * 33 + k];
        float w1 = Wsh[(tx + 32) * 33 + k];
        float w2 = Wsh[(tx + 64) * 33 + k];
        float w3 = Wsh[(tx + 96) * 33 + k];
#pragma unroll
        for (int i = 0; i < 8; i++) {
            float xv = xsh[(ty * 8 + i) * 33 + k];
            acc[i][0] += xv * w0;
            acc[i][1] += xv * w1;
            acc[i][2] += xv * w2;
            acc[i][3] += xv * w3;
        }
    }

    float asv[4], adv[4];
#pragma unroll
    for (int j = 0; j < 4; j++) { asv[j] = as_[32 * j + tx]; adv[j] = ad_[32 * j + tx]; }

#pragma unroll
    for (int i = 0; i < 8; i++) {
        int row = ty * 8 + i;
        bool ok = row < nrows;
        __half* orow = xs + (size_t)(n0 + row) * 128;
#pragma unroll
        for (int j = 0; j < 4; j++) {
            if (ok) orow[32 * j + tx] = __float2half(acc[i][j]);
            float vs = acc[i][j] * asv[j];
            float vd = acc[i][j] * adv[j];
#pragma unroll
            for (int off = 16; off; off >>= 1) {
                vs += __shfl_xor(vs, off);
                vd += __shfl_xor(vd, off);
            }
            if (ok && tx == 0) {
                asrc[(size_t)(n0 + row) * 4 + j] = vs;
                adst[(size_t)(n0 + row) * 4 + j] = vd;
            }
        }
    }
}

// ---- fused gather: 16 lanes per edge, 4 edges per wave-step.
//      Lane owns 8 channels (16B fp16); head = (lane&15)>>2 is lane-constant. ----
__global__ void k_gather(const int2* __restrict__ epk, const int* __restrict__ rowptr,
                         const __half* __restrict__ xs,
                         const float* __restrict__ asrc, const float* __restrict__ adst,
                         const float* __restrict__ wedot, const float* __restrict__ bias,
                         float* __restrict__ out, int N) {
    int node = blockIdx.x * 4 + (threadIdx.x >> 6);
    if (node >= N) return;
    int l = threadIdx.x & 63;
    int q = l >> 4;          // edge slot 0..3
    int p = l & 15;          // lane within edge; channels p*8..p*8+7
    int h = p >> 2;          // head of these channels
    float wd = wedot[h];
    float ad = adst[(size_t)node * 4 + h];
    int beg = rowptr[node], end = rowptr[node + 1];

    float a0 = 0.f, a1 = 0.f, a2 = 0.f, a3 = 0.f;
    float a4 = 0.f, a5 = 0.f, a6 = 0.f, a7 = 0.f, ds = 0.f;
    for (int i = beg; i < end; i += 4) {
        int idx = i + q;
        bool valid = idx < end;
        int2 e = epk[valid ? idx : end - 1];
        int s = e.x;
        float as = asrc[(size_t)s * 4 + h];
        float al = as + ad + __int_as_float(e.y) * wd;
        al = fmaxf(al, 0.2f * al);
        float w = valid ? __expf(al) : 0.f;
        uint4 raw = reinterpret_cast<const uint4*>(xs + (size_t)s * 128)[p];
        const __half2* hp = reinterpret_cast<const __half2*>(&raw);
        float2 f0 = __half22float2(hp[0]);
        float2 f1 = __half22float2(hp[1]);
        float2 f2 = __half22float2(hp[2]);
        float2 f3 = __half22float2(hp[3]);
        a0 += w * f0.x; a1 += w * f0.y;
        a2 += w * f1.x; a3 += w * f1.y;
        a4 += w * f2.x; a5 += w * f2.y;
        a6 += w * f3.x; a7 += w * f3.y;
        ds += w;
    }
    // reduce across the 4 edge slots (lane bits 4,5)
    a0 += __shfl_xor(a0, 16); a1 += __shfl_xor(a1, 16);
    a2 += __shfl_xor(a2, 16); a3 += __shfl_xor(a3, 16);
    a4 += __shfl_xor(a4, 16); a5 += __shfl_xor(a5, 16);
    a6 += __shfl_xor(a6, 16); a7 += __shfl_xor(a7, 16);
    ds += __shfl_xor(ds, 16);
    a0 += __shfl_xor(a0, 32); a1 += __shfl_xor(a1, 32);
    a2 += __shfl_xor(a2, 32); a3 += __shfl_xor(a3, 32);
    a4 += __shfl_xor(a4, 32); a5 += __shfl_xor(a5, 32);
    a6 += __shfl_xor(a6, 32); a7 += __shfl_xor(a7, 32);
    ds += __shfl_xor(ds, 32);
    float inv = 1.f / (ds + GAT_EPS);
    a0 *= inv; a1 *= inv; a2 *= inv; a3 *= inv;
    a4 *= inv; a5 *= inv; a6 *= inv; a7 *= inv;
    // head-mean over lane bits 2,3 of p
    a0 += __shfl_xor(a0, 4); a1 += __shfl_xor(a1, 4);
    a2 += __shfl_xor(a2, 4); a3 += __shfl_xor(a3, 4);
    a4 += __shfl_xor(a4, 4); a5 += __shfl_xor(a5, 4);
    a6 += __shfl_xor(a6, 4); a7 += __shfl_xor(a7, 4);
    a0 += __shfl_xor(a0, 8); a1 += __shfl_xor(a1, 8);
    a2 += __shfl_xor(a2, 8); a3 += __shfl_xor(a3, 8);
    a4 += __shfl_xor(a4, 8); a5 += __shfl_xor(a5, 8);
    a6 += __shfl_xor(a6, 8); a7 += __shfl_xor(a7, 8);
    if (l < 4) {
        int c0 = l * 8;
        float4 r0, r1;
        r0.x = fmaxf(0.25f * a0 + bias[c0 + 0], 0.f);
        r0.y = fmaxf(0.25f * a1 + bias[c0 + 1], 0.f);
        r0.z = fmaxf(0.25f * a2 + bias[c0 + 2], 0.f);
        r0.w = fmaxf(0.25f * a3 + bias[c0 + 3], 0.f);
        r1.x = fmaxf(0.25f * a4 + bias[c0 + 4], 0.f);
        r1.y = fmaxf(0.25f * a5 + bias[c0 + 5], 0.f);
        r1.z = fmaxf(0.25f * a6 + bias[c0 + 6], 0.f);
        r1.w = fmaxf(0.25f * a7 + bias[c0 + 7], 0.f);
        float4* op = reinterpret_cast<float4*>(out + (size_t)node * 32 + c0);
        op[0] = r0;
        op[1] = r1;
    }
}

extern "C" void kernel_launch(void* const* d_in, const int* in_sizes, int n_in,
                              void* d_out, int out_size, void* d_ws, size_t ws_size,
                              hipStream_t stream) {
    const float* x   = (const float*)d_in[0];
    const int*   ei  = (const int*)d_in[1];
    const float* ewt = (const float*)d_in[2];
    const float* w1  = (const float*)d_in[3];
    const float* we1 = (const float*)d_in[4];
    const float* as1 = (const float*)d_in[5];
    const float* ad1 = (const float*)d_in[6];
    const float* ae1 = (const float*)d_in[7];
    const float* b1  = (const float*)d_in[8];
    const float* w2  = (const float*)d_in[9];
    const float* we2 = (const float*)d_in[10];
    const float* as2 = (const float*)d_in[11];
    const float* ad2 = (const float*)d_in[12];
    const float* ae2 = (const float*)d_in[13];
    const float* b2  = (const float*)d_in[14];

    const int N = in_sizes[0] / 64;
    const int E = in_sizes[1] / 2;
    const int Etot = E + N;
    const int* srcI = ei;
    const int* dstI = ei + E;
    const int nb = (N + SCAN_BS - 1) / SCAN_BS;

    char* base = (char*)d_ws;
    size_t off = 0;
    auto alloc = [&](size_t bytes) { char* p = base + off; off += (bytes + 15) & ~(size_t)15; return p; };
    __half* xs    = (__half*)alloc((size_t)N * 128 * sizeof(__half));
    float* h1     = (float*)alloc((size_t)N * 32 * sizeof(float));
    float* asrc   = (float*)alloc((size_t)N * 4 * sizeof(float));
    float* adst   = (float*)alloc((size_t)N * 4 * sizeof(float));
    float* loopat = (float*)alloc((size_t)N * sizeof(float));
    unsigned long long* pk = (unsigned long long*)alloc((size_t)N * sizeof(unsigned long long));
    int*   cnt    = (int*)alloc((size_t)N * sizeof(int));
    int*   incl   = (int*)alloc((size_t)N * sizeof(int));
    int*   bsum   = (int*)alloc(512 * sizeof(int));
    int*   rowptr = (int*)alloc((size_t)(N + 1) * sizeof(int));
    int*   pos    = (int*)alloc((size_t)E * sizeof(int));
    int2*  epk    = (int2*)alloc((size_t)Etot * sizeof(int2));
    float* wedot  = (float*)alloc(8 * sizeof(float));

    float* outF = (float*)d_out;

    hipMemsetAsync(pk, 0, (size_t)N * sizeof(unsigned long long), stream);

    const int gemmb = (N + 63) / 64;
    const int histb = (E + 255) / 256;
    const int G = gemmb > (histb + 3) / 4 ? gemmb : (histb + 3) / 4;
    const int gb = (N + 3) / 4;

    // FUSED layer-1 GEMM + edge histogram (independent work, complementary pipes)
    k_gemm1h<<<5 * G, 256, 0, stream>>>(x, w1, as1, ad1, xs, asrc, adst, N, gemmb,
                                        dstI, ewt, pk, pos, E);

    // CSR build
    k_scanA<<<nb, SCAN_BS, 0, stream>>>(pk, loopat, cnt, incl, bsum, N);
    k_scanB<<<1, 512, 0, stream>>>(bsum, nb, we1, ae1, we2, ae2, wedot);
    k_scanC<<<nb, SCAN_BS, 0, stream>>>(cnt, incl, bsum, rowptr, N, Etot);
    k_scatter<<<(Etot + 255) / 256, 256, 0, stream>>>(srcI, dstI, ewt, loopat,
                                                      cnt, pos, rowptr, epk, E, Etot);

    // layer 1 gather
    k_gather<<<gb, 256, 0, stream>>>(epk, rowptr, xs, asrc, adst,
                                     wedot + 0, b1, h1, N);

    // layer 2
    k_gemm2<<<gemmb, 256, 0, stream>>>(h1, w2, as2, ad2, xs, asrc, adst, N);
    k_gather<<<gb, 256, 0, stream>>>(epk, rowptr, xs, asrc, adst,
                                     wedot + 4, b2, outF, N);
}

// Round 12
// 322.151 us; speedup vs baseline: 6.2215x; 1.0485x over previous
//
#include <hip/hip_runtime.h>
#include <hip/hip_fp16.h>
#include <cstddef>

#define GAT_EPS 1e-16f
#define SCAN_BS 256

// ---- decode pk -> cnt/loopat; exclusive scan of (cnt+1) part A ----
__global__ void k_scanA(const unsigned long long* __restrict__ pk,
                        float* __restrict__ loopat, int* __restrict__ cnt,
                        int* __restrict__ incl, int* __restrict__ bsum, int N) {
    __shared__ int sh[SCAN_BS];
    int i = blockIdx.x * SCAN_BS + threadIdx.x;
    int cv = 0;
    if (i < N) {
        unsigned long long v = pk[i];
        cv = (int)(v >> 44);
        float sum = (float)(v & ((1ULL << 44) - 1)) * (1.0f / 16777216.0f);
        loopat[i] = sum / fmaxf((float)cv, 1.0f);
        cnt[i] = cv;
    }
    int v = (i < N) ? cv + 1 : 0;
    sh[threadIdx.x] = v;
    __syncthreads();
    for (int off = 1; off < SCAN_BS; off <<= 1) {
        int t = (threadIdx.x >= off) ? sh[threadIdx.x - off] : 0;
        __syncthreads();
        sh[threadIdx.x] += t;
        __syncthreads();
    }
    if (i < N) incl[i] = sh[threadIdx.x];
    if (threadIdx.x == SCAN_BS - 1) bsum[blockIdx.x] = sh[threadIdx.x];
}

// ---- scan part B (single block) + folded wedot computation ----
__global__ void k_scanB(int* __restrict__ bsum, int nb,
                        const float* __restrict__ we1, const float* __restrict__ ae1,
                        const float* __restrict__ we2, const float* __restrict__ ae2,
                        float* __restrict__ wd) {
    int t = threadIdx.x;
    if (t < 128) {
        float v1 = we1[t] * ae1[t];
        float v2 = we2[t] * ae2[t];
#pragma unroll
        for (int off = 16; off; off >>= 1) {
            v1 += __shfl_xor(v1, off);
            v2 += __shfl_xor(v2, off);
        }
        if ((t & 31) == 0) { wd[t >> 5] = v1; wd[4 + (t >> 5)] = v2; }
    }
    __shared__ int sh[512];
    int v = (t < nb) ? bsum[t] : 0;
    sh[t] = v;
    __syncthreads();
    for (int off = 1; off < 512; off <<= 1) {
        int u = (t >= off) ? sh[t - off] : 0;
        __syncthreads();
        sh[t] += u;
        __syncthreads();
    }
    if (t < nb) bsum[t] = sh[t] - v;
}

__global__ void k_scanC(const int* __restrict__ cnt, const int* __restrict__ incl,
                        const int* __restrict__ bsum, int* __restrict__ rowptr,
                        int N, int Etot) {
    int i = blockIdx.x * SCAN_BS + threadIdx.x;
    if (i < N) rowptr[i] = bsum[blockIdx.x] + incl[i] - (cnt[i] + 1);
    if (i == N - 1) rowptr[N] = Etot;
}

// ---- scatter edges into CSR segments, atomic-free (slots precomputed) ----
__global__ void k_scatter(const int* __restrict__ src, const int* __restrict__ dst,
                          const float* __restrict__ ew, const float* __restrict__ loopat,
                          const int* __restrict__ cnt, const int* __restrict__ pos,
                          const int* __restrict__ rowptr, int2* __restrict__ epk,
                          int E, int Etot) {
    int e = blockIdx.x * blockDim.x + threadIdx.x;
    if (e >= Etot) return;
    int s, d, p; float ea;
    if (e < E) { s = src[e]; d = dst[e]; ea = ew[e]; p = pos[e]; }
    else       { s = e - E; d = s;       ea = loopat[s]; p = cnt[d]; }
    int2 q; q.x = s; q.y = __float_as_int(ea);
    epk[rowptr[d] + p] = q;
}

// ---- FUSED: layer-1 GEMM (+attn dots) AND edge histogram.
//      W staged fp16 k-major interleaved -> 33.5 KB LDS, 4 blocks/CU. ----
__global__ __launch_bounds__(256, 2)
void k_gemm1h(const float* __restrict__ x, const float* __restrict__ W,
              const float* __restrict__ as_, const float* __restrict__ ad_,
              __half* __restrict__ xs, float* __restrict__ asrc,
              float* __restrict__ adst, int N, int gemmb,
              const int* __restrict__ dst, const float* __restrict__ ew,
              unsigned long long* __restrict__ pk, int* __restrict__ pos, int E) {
    int g = blockIdx.x / 5;
    int r = blockIdx.x % 5;
    if (r != 0) {
        int i = (g * 4 + r - 1) * 256 + threadIdx.x;
        if (i < E) {
            int d = dst[i];
            unsigned long long add = (1ULL << 44) |
                (unsigned long long)(ew[i] * 16777216.0f + 0.5f);
            unsigned long long old = atomicAdd(&pk[d], add);
            pos[i] = (int)(old >> 44);
        }
        return;
    }
    if (g >= gemmb) return;

    int n0 = g * 64;
    int t = threadIdx.x;          // 256
    int tx = t & 31;              // col lane
    int ty = t >> 5;              // row group 0..7
    __shared__ __half Wh[64 * 132];   // [k][cperm], cperm=(c&31)*4+(c>>5)
    __shared__ float xsh[64 * 65];
    int nrows = min(64, N - n0);
    for (int j = t; j < 8192; j += 256) {
        int c = j >> 6, k = j & 63;
        Wh[k * 132 + ((c & 31) << 2) + (c >> 5)] = __float2half(W[j]);
    }
    const float* xg = x + (size_t)n0 * 64;
    for (int j = t; j < nrows * 64; j += 256) xsh[(j >> 6) * 65 + (j & 63)] = xg[j];
    __syncthreads();

    float acc[8][4];
#pragma unroll
    for (int i = 0; i < 8; i++)
#pragma unroll
        for (int j = 0; j < 4; j++) acc[i][j] = 0.f;

#pragma unroll 4
    for (int k = 0; k < 64; k++) {
        const __half2* wp = reinterpret_cast<const __half2*>(&Wh[k * 132 + (tx << 2)]);
        float2 wf0 = __half22float2(wp[0]);
        float2 wf1 = __half22float2(wp[1]);
#pragma unroll
        for (int i = 0; i < 8; i++) {
            float xv = xsh[(ty * 8 + i) * 65 + k];
            acc[i][0] += xv * wf0.x;
            acc[i][1] += xv * wf0.y;
            acc[i][2] += xv * wf1.x;
            acc[i][3] += xv * wf1.y;
        }
    }

    float asv[4], adv[4];
#pragma unroll
    for (int j = 0; j < 4; j++) { asv[j] = as_[32 * j + tx]; adv[j] = ad_[32 * j + tx]; }

#pragma unroll
    for (int i = 0; i < 8; i++) {
        int row = ty * 8 + i;
        bool ok = row < nrows;
        __half* orow = xs + (size_t)(n0 + row) * 128;
#pragma unroll
        for (int j = 0; j < 4; j++) {
            if (ok) orow[32 * j + tx] = __float2half(acc[i][j]);
            float vs = acc[i][j] * asv[j];
            float vd = acc[i][j] * adv[j];
#pragma unroll
            for (int off = 16; off; off >>= 1) {
                vs += __shfl_xor(vs, off);
                vd += __shfl_xor(vd, off);
            }
            if (ok && tx == 0) {
                asrc[(size_t)(n0 + row) * 4 + j] = vs;
                adst[(size_t)(n0 + row) * 4 + j] = vd;
            }
        }
    }
}

// ---- layer-2 GEMM + fused attn dots: xs = h1 @ W2^T (K=32), W2 fp16 LDS. ----
__global__ __launch_bounds__(256, 2)
void k_gemm2(const float* __restrict__ h1, const float* __restrict__ W2,
             const float* __restrict__ as_, const float* __restrict__ ad_,
             __half* __restrict__ xs, float* __restrict__ asrc,
             float* __restrict__ adst, int N) {
    int n0 = blockIdx.x * 64;
    int t = threadIdx.x;
    int tx = t & 31;
    int ty = t >> 5;
    __shared__ __half Wh[32 * 132];
    __shared__ float xsh[64 * 33];
    int nrows = min(64, N - n0);
    for (int j = t; j < 4096; j += 256) {
        int c = j >> 5, k = j & 31;
        Wh[k * 132 + ((c & 31) << 2) + (c >> 5)] = __float2half(W2[j]);
    }
    const float* xg = h1 + (size_t)n0 * 32;
    for (int j = t; j < nrows * 32; j += 256) xsh[(j >> 5) * 33 + (j & 31)] = xg[j];
    __syncthreads();

    float acc[8][4];
#pragma unroll
    for (int i = 0; i < 8; i++)
#pragma unroll
        for (int j = 0; j < 4; j++) acc[i][j] = 0.f;

#pragma unroll 4
    for (int k = 0; k < 32; k++) {
        const __half2* wp = reinterpret_cast<const __half2*>(&Wh[k * 132 + (tx << 2)]);
        float2 wf0 = __half22float2(wp[0]);
        float2 wf1 = __half22float2(wp[1]);
#pragma unroll
        for (int i = 0; i < 8; i++) {
            float xv = xsh[(ty * 8 + i) * 33 + k];
            acc[i][0] += xv * wf0.x;
            acc[i][1] += xv * wf0.y;
            acc[i][2] += xv * wf1.x;
            acc[i][3] += xv * wf1.y;
        }
    }

    float asv[4], adv[4];
#pragma unroll
    for (int j = 0; j < 4; j++) { asv[j] = as_[32 * j + tx]; adv[j] = ad_[32 * j + tx]; }

#pragma unroll
    for (int i = 0; i < 8; i++) {
        int row = ty * 8 + i;
        bool ok = row < nrows;
        __half* orow = xs + (size_t)(n0 + row) * 128;
#pragma unroll
        for (int j = 0; j < 4; j++) {
            if (ok) orow[32 * j + tx] = __float2half(acc[i][j]);
            float vs = acc[i][j] * asv[j];
            float vd = acc[i][j] * adv[j];
#pragma unroll
            for (int off = 16; off; off >>= 1) {
                vs += __shfl_xor(vs, off);
                vd += __shfl_xor(vd, off);
            }
            if (ok && tx == 0) {
                asrc[(size_t)(n0 + row) * 4 + j] = vs;
                adst[(size_t)(n0 + row) * 4 + j] = vd;
            }
        }
    }
}

// ---- fused gather: 16 lanes per edge, 4 edges per wave-step, unroll 2. ----
__global__ void k_gather(const int2* __restrict__ epk, const int* __restrict__ rowptr,
                         const __half* __restrict__ xs,
                         const float* __restrict__ asrc, const float* __restrict__ adst,
                         const float* __restrict__ wedot, const float* __restrict__ bias,
                         float* __restrict__ out, int N) {
    int node = blockIdx.x * 4 + (threadIdx.x >> 6);
    if (node >= N) return;
    int l = threadIdx.x & 63;
    int q = l >> 4;          // edge slot 0..3
    int p = l & 15;          // lane within edge; channels p*8..p*8+7
    int h = p >> 2;          // head of these channels
    float wd = wedot[h];
    float ad = adst[(size_t)node * 4 + h];
    int beg = rowptr[node], end = rowptr[node + 1];

    float a0 = 0.f, a1 = 0.f, a2 = 0.f, a3 = 0.f;
    float a4 = 0.f, a5 = 0.f, a6 = 0.f, a7 = 0.f, ds = 0.f;
#pragma unroll 2
    for (int i = beg; i < end; i += 4) {
        int idx = i + q;
        bool valid = idx < end;
        int2 e = epk[valid ? idx : end - 1];
        int s = e.x;
        float as = asrc[(size_t)s * 4 + h];
        float al = as + ad + __int_as_float(e.y) * wd;
        al = fmaxf(al, 0.2f * al);
        float w = valid ? __expf(al) : 0.f;
        uint4 raw = reinterpret_cast<const uint4*>(xs + (size_t)s * 128)[p];
        const __half2* hp = reinterpret_cast<const __half2*>(&raw);
        float2 f0 = __half22float2(hp[0]);
        float2 f1 = __half22float2(hp[1]);
        float2 f2 = __half22float2(hp[2]);
        float2 f3 = __half22float2(hp[3]);
        a0 += w * f0.x; a1 += w * f0.y;
        a2 += w * f1.x; a3 += w * f1.y;
        a4 += w * f2.x; a5 += w * f2.y;
        a6 += w * f3.x; a7 += w * f3.y;
        ds += w;
    }
    // reduce across the 4 edge slots (lane bits 4,5)
    a0 += __shfl_xor(a0, 16); a1 += __shfl_xor(a1, 16);
    a2 += __shfl_xor(a2, 16); a3 += __shfl_xor(a3, 16);
    a4 += __shfl_xor(a4, 16); a5 += __shfl_xor(a5, 16);
    a6 += __shfl_xor(a6, 16); a7 += __shfl_xor(a7, 16);
    ds += __shfl_xor(ds, 16);
    a0 += __shfl_xor(a0, 32); a1 += __shfl_xor(a1, 32);
    a2 += __shfl_xor(a2, 32); a3 += __shfl_xor(a3, 32);
    a4 += __shfl_xor(a4, 32); a5 += __shfl_xor(a5, 32);
    a6 += __shfl_xor(a6, 32); a7 += __shfl_xor(a7, 32);
    ds += __shfl_xor(ds, 32);
    float inv = 1.f / (ds + GAT_EPS);
    a0 *= inv; a1 *= inv; a2 *= inv; a3 *= inv;
    a4 *= inv; a5 *= inv; a6 *= inv; a7 *= inv;
    // head-mean over lane bits 2,3 of p
    a0 += __shfl_xor(a0, 4); a1 += __shfl_xor(a1, 4);
    a2 += __shfl_xor(a2, 4); a3 += __shfl_xor(a3, 4);
    a4 += __shfl_xor(a4, 4); a5 += __shfl_xor(a5, 4);
    a6 += __shfl_xor(a6, 4); a7 += __shfl_xor(a7, 4);
    a0 += __shfl_xor(a0, 8); a1 += __shfl_xor(a1, 8);
    a2 += __shfl_xor(a2, 8); a3 += __shfl_xor(a3, 8);
    a4 += __shfl_xor(a4, 8); a5 += __shfl_xor(a5, 8);
    a6 += __shfl_xor(a6, 8); a7 += __shfl_xor(a7, 8);
    if (l < 4) {
        int c0 = l * 8;
        float4 r0, r1;
        r0.x = fmaxf(0.25f * a0 + bias[c0 + 0], 0.f);
        r0.y = fmaxf(0.25f * a1 + bias[c0 + 1], 0.f);
        r0.z = fmaxf(0.25f * a2 + bias[c0 + 2], 0.f);
        r0.w = fmaxf(0.25f * a3 + bias[c0 + 3], 0.f);
        r1.x = fmaxf(0.25f * a4 + bias[c0 + 4], 0.f);
        r1.y = fmaxf(0.25f * a5 + bias[c0 + 5], 0.f);
        r1.z = fmaxf(0.25f * a6 + bias[c0 + 6], 0.f);
        r1.w = fmaxf(0.25f * a7 + bias[c0 + 7], 0.f);
        float4* op = reinterpret_cast<float4*>(out + (size_t)node * 32 + c0);
        op[0] = r0;
        op[1] = r1;
    }
}

extern "C" void kernel_launch(void* const* d_in, const int* in_sizes, int n_in,
                              void* d_out, int out_size, void* d_ws, size_t ws_size,
                              hipStream_t stream) {
    const float* x   = (const float*)d_in[0];
    const int*   ei  = (const int*)d_in[1];
    const float* ewt = (const float*)d_in[2];
    const float* w1  = (const float*)d_in[3];
    const float* we1 = (const float*)d_in[4];
    const float* as1 = (const float*)d_in[5];
    const float* ad1 = (const float*)d_in[6];
    const float* ae1 = (const float*)d_in[7];
    const float* b1  = (const float*)d_in[8];
    const float* w2  = (const float*)d_in[9];
    const float* we2 = (const float*)d_in[10];
    const float* as2 = (const float*)d_in[11];
    const float* ad2 = (const float*)d_in[12];
    const float* ae2 = (const float*)d_in[13];
    const float* b2  = (const float*)d_in[14];

    const int N = in_sizes[0] / 64;
    const int E = in_sizes[1] / 2;
    const int Etot = E + N;
    const int* srcI = ei;
    const int* dstI = ei + E;
    const int nb = (N + SCAN_BS - 1) / SCAN_BS;

    char* base = (char*)d_ws;
    size_t off = 0;
    auto alloc = [&](size_t bytes) { char* p = base + off; off += (bytes + 15) & ~(size_t)15; return p; };
    __half* xs    = (__half*)alloc((size_t)N * 128 * sizeof(__half));
    float* h1     = (float*)alloc((size_t)N * 32 * sizeof(float));
    float* asrc   = (float*)alloc((size_t)N * 4 * sizeof(float));
    float* adst   = (float*)alloc((size_t)N * 4 * sizeof(float));
    float* loopat = (float*)alloc((size_t)N * sizeof(float));
    unsigned long long* pk = (unsigned long long*)alloc((size_t)N * sizeof(unsigned long long));
    int*   cnt    = (int*)alloc((size_t)N * sizeof(int));
    int*   incl   = (int*)alloc((size_t)N * sizeof(int));
    int*   bsum   = (int*)alloc(512 * sizeof(int));
    int*   rowptr = (int*)alloc((size_t)(N + 1) * sizeof(int));
    int*   pos    = (int*)alloc((size_t)E * sizeof(int));
    int2*  epk    = (int2*)alloc((size_t)Etot * sizeof(int2));
    float* wedot  = (float*)alloc(8 * sizeof(float));

    float* outF = (float*)d_out;

    hipMemsetAsync(pk, 0, (size_t)N * sizeof(unsigned long long), stream);

    const int gemmb = (N + 63) / 64;
    const int histb = (E + 255) / 256;
    const int G = gemmb > (histb + 3) / 4 ? gemmb : (histb + 3) / 4;
    const int gb = (N + 3) / 4;

    // FUSED layer-1 GEMM + edge histogram (independent work, complementary pipes)
    k_gemm1h<<<5 * G, 256, 0, stream>>>(x, w1, as1, ad1, xs, asrc, adst, N, gemmb,
                                        dstI, ewt, pk, pos, E);

    // CSR build
    k_scanA<<<nb, SCAN_BS, 0, stream>>>(pk, loopat, cnt, incl, bsum, N);
    k_scanB<<<1, 512, 0, stream>>>(bsum, nb, we1, ae1, we2, ae2, wedot);
    k_scanC<<<nb, SCAN_BS, 0, stream>>>(cnt, incl, bsum, rowptr, N, Etot);
    k_scatter<<<(Etot + 255) / 256, 256, 0, stream>>>(srcI, dstI, ewt, loopat,
                                                      cnt, pos, rowptr, epk, E, Etot);

    // layer 1 gather
    k_gather<<<gb, 256, 0, stream>>>(epk, rowptr, xs, asrc, adst,
                                     wedot + 0, b1, h1, N);

    // layer 2
    k_gemm2<<<gemmb, 256, 0, stream>>>(h1, w2, as2, ad2, xs, asrc, adst, N);
    k_gather<<<gb, 256, 0, stream>>>(epk, rowptr, xs, asrc, adst,
                                     wedot + 4, b2, outF, N);
}